// Round 3
// baseline (1513.231 us; speedup 1.0000x reference)
//
#include <hip/hip_runtime.h>
#include <hip/hip_bf16.h>

#define NN 50000
#define NE 400000

__device__ __forceinline__ float geluf(float x){ return 0.5f*x*(1.0f+erff(x*0.70710678118654752440f)); }

// ---------------- K1: H = gelu(X @ W1^T + b1) ----------------
__global__ __launch_bounds__(256) void k_ff1(const float* __restrict__ X,
    const float* __restrict__ W1, const float* __restrict__ b1,
    float* __restrict__ H)
{
  extern __shared__ float smem[]; // [128][128]: smem[k*128+c] = W1[c*128+k]
  for (int j = threadIdx.x; j < 128*128; j += 256){
    int k = j >> 7, c = j & 127;
    smem[j] = W1[c*128 + k];
  }
  __syncthreads();
  const int half = threadIdx.x >> 7;
  const int c = threadIdx.x & 127;
  const float bias = b1[c];
  for (int row = blockIdx.x*2 + half; row < NN; row += gridDim.x*2){
    const float* xr = X + (size_t)row*128;
    float acc = 0.f;
    #pragma unroll
    for (int k4 = 0; k4 < 128; k4 += 4){
      float4 xv = *(const float4*)(xr + k4);
      acc += xv.x * smem[(k4+0)*128 + c];
      acc += xv.y * smem[(k4+1)*128 + c];
      acc += xv.z * smem[(k4+2)*128 + c];
      acc += xv.w * smem[(k4+3)*128 + c];
    }
    H[(size_t)row*128 + c] = geluf(acc + bias);
  }
}

// ---------------- sort edges by dst: hist -> scan -> fill ----------------
__global__ void k_hist(const int* __restrict__ dst, int* __restrict__ deg){
  int e = blockIdx.x*256 + threadIdx.x;
  if (e < NE) atomicAdd(&deg[dst[e]], 1);
}

__global__ __launch_bounds__(1024) void k_scan(const int* __restrict__ deg, int* __restrict__ offs){
  __shared__ int sd[1024];
  __shared__ int sbase;
  if (threadIdx.x == 0) sbase = 0;
  __syncthreads();
  for (int chunk = 0; chunk < NN; chunk += 1024){
    int i = chunk + threadIdx.x;
    int v = (i < NN) ? deg[i] : 0;
    sd[threadIdx.x] = v;
    __syncthreads();
    for (int ofs = 1; ofs < 1024; ofs <<= 1){
      int t = (threadIdx.x >= ofs) ? sd[threadIdx.x - ofs] : 0;
      __syncthreads();
      sd[threadIdx.x] += t;
      __syncthreads();
    }
    if (i < NN) offs[i] = sbase + sd[threadIdx.x] - v;
    __syncthreads();
    if (threadIdx.x == 1023) sbase += sd[1023];
    __syncthreads();
  }
  if (threadIdx.x == 0) offs[NN] = sbase;
}

__global__ void k_fill(const int* __restrict__ dst, const int* __restrict__ offs,
                       int* __restrict__ cur, int* __restrict__ elist){
  int e = blockIdx.x*256 + threadIdx.x;
  if (e < NE){
    int d = dst[e];
    int p = atomicAdd(&cur[d], 1);
    elist[offs[d] + p] = e;
  }
}

// ---------------- K2a: W_tar[e] = gelu(H[src] @ WA^T) @ WB^T ----------------
__global__ __launch_bounds__(256) void k_edge(const float* __restrict__ H,
    const float* __restrict__ WA, const float* __restrict__ WB,
    const int* __restrict__ src, float* __restrict__ Wtar)
{
  extern __shared__ float smem[]; // [128][128]: smem[k*128+h] = WA[h*128+k]
  for (int j = threadIdx.x; j < 128*128; j += 256){
    int k = j >> 7, h = j & 127;
    smem[j] = WA[h*128 + k];
  }
  const int lane = threadIdx.x & 63;
  const int wave = threadIdx.x >> 6;
  float wb0[4], wb1[4];
  #pragma unroll
  for (int m = 0; m < 4; m++){
    wb0[m] = WB[m*128 + lane];
    wb1[m] = WB[m*128 + 64 + lane];
  }
  __syncthreads();
  for (int eb = (blockIdx.x*4 + wave)*4; eb < NE; eb += gridDim.x*16){
    const float* h0 = H + (size_t)src[eb+0]*128;
    const float* h1 = H + (size_t)src[eb+1]*128;
    const float* h2 = H + (size_t)src[eb+2]*128;
    const float* h3 = H + (size_t)src[eb+3]*128;
    float a0x=0,a0y=0,a1x=0,a1y=0,a2x=0,a2y=0,a3x=0,a3y=0;
    for (int k4 = 0; k4 < 128; k4 += 4){
      float4 v0 = *(const float4*)(h0 + k4);
      float4 v1 = *(const float4*)(h1 + k4);
      float4 v2 = *(const float4*)(h2 + k4);
      float4 v3 = *(const float4*)(h3 + k4);
      #define KSTEP(F, KI) { \
        float wa = smem[(k4+KI)*128 + lane]; \
        float wb = smem[(k4+KI)*128 + 64 + lane]; \
        a0x += v0.F*wa; a0y += v0.F*wb; \
        a1x += v1.F*wa; a1y += v1.F*wb; \
        a2x += v2.F*wa; a2y += v2.F*wb; \
        a3x += v3.F*wa; a3y += v3.F*wb; }
      KSTEP(x,0) KSTEP(y,1) KSTEP(z,2) KSTEP(w,3)
      #undef KSTEP
    }
    float t0x = geluf(a0x), t0y = geluf(a0y);
    float t1x = geluf(a1x), t1y = geluf(a1y);
    float t2x = geluf(a2x), t2y = geluf(a2y);
    float t3x = geluf(a3x), t3y = geluf(a3y);
    float r[16];
    #pragma unroll
    for (int m = 0; m < 4; m++){
      r[0*4+m] = t0x*wb0[m] + t0y*wb1[m];
      r[1*4+m] = t1x*wb0[m] + t1y*wb1[m];
      r[2*4+m] = t2x*wb0[m] + t2y*wb1[m];
      r[3*4+m] = t3x*wb0[m] + t3y*wb1[m];
    }
    #pragma unroll
    for (int s = 1; s < 64; s <<= 1){
      #pragma unroll
      for (int q = 0; q < 16; q++)
        r[q] += __shfl_xor(r[q], s, 64);
    }
    float outv = 0.f;
    #pragma unroll
    for (int q = 0; q < 16; q++)
      if (lane == q) outv = r[q];
    if (lane < 16) Wtar[(size_t)eb*4 + lane] = outv;
  }
}

// ------- K2b: per-node register aggregation; GA = gelu(agg_node_mean) -------
__global__ __launch_bounds__(256) void k_agg(const float* __restrict__ H,
    const float* __restrict__ Wtar, const int* __restrict__ src,
    const int* __restrict__ offs, const int* __restrict__ elist,
    float* __restrict__ GA)
{
  const int lane = threadIdx.x & 63;
  const int wave = threadIdx.x >> 6;
  for (int v = blockIdx.x*4 + wave; v < NN; v += gridDim.x*4){
    int e0 = offs[v], e1 = offs[v+1];
    float ax0=0, ax1=0, ax2=0, ax3=0;   // h = 2*lane
    float ay0=0, ay1=0, ay2=0, ay3=0;   // h = 2*lane+1
    float s0=0, s1=0, s2=0, s3=0;
    for (int idx = e0; idx < e1; idx++){
      int e = elist[idx];
      int sn = src[e];
      float2 hv = *(const float2*)(H + (size_t)sn*128 + lane*2);
      float4 wt = *(const float4*)(Wtar + (size_t)e*4);
      ax0 += hv.x*wt.x; ax1 += hv.x*wt.y; ax2 += hv.x*wt.z; ax3 += hv.x*wt.w;
      ay0 += hv.y*wt.x; ay1 += hv.y*wt.y; ay2 += hv.y*wt.z; ay3 += hv.y*wt.w;
      s0 += wt.x; s1 += wt.y; s2 += wt.z; s3 += wt.w;
    }
    float inv = 1.0f / fmaxf((float)(e1 - e0), 1.0f);
    float ox = geluf(ax0)*s0 + geluf(ax1)*s1 + geluf(ax2)*s2 + geluf(ax3)*s3;
    float oy = geluf(ay0)*s0 + geluf(ay1)*s1 + geluf(ay2)*s2 + geluf(ay3)*s3;
    float2 res;
    res.x = geluf(ox * inv);
    res.y = geluf(oy * inv);
    *(float2*)(GA + (size_t)v*128 + lane*2) = res;
  }
}

// ------- K3: out = [GA, gelu(H)] @ W2^T + b2  (GA already gelu'd) -------
__global__ __launch_bounds__(256) void k_ff2(const float* __restrict__ GA,
    const float* __restrict__ H, const float* __restrict__ W2,
    const float* __restrict__ b2, float* __restrict__ out)
{
  extern __shared__ float smem[]; // [256][128]: smem[j*128+o] = W2[o*256+j]  (128 KB)
  for (int t = threadIdx.x; t < 256*128; t += 256){
    int j = t >> 7, o = t & 127;
    smem[t] = W2[o*256 + j];
  }
  __syncthreads();
  const int lane = threadIdx.x & 63;
  const int wave = threadIdx.x >> 6;
  const float bx = b2[lane*2];
  const float by = b2[lane*2+1];
  for (int vp = blockIdx.x*8 + wave*2; vp < NN; vp += gridDim.x*8){
    const float* ga0 = GA + (size_t)vp*128;
    const float* ga1 = GA + (size_t)(vp+1)*128;
    const float* gh0 = H + (size_t)vp*128;
    const float* gh1 = H + (size_t)(vp+1)*128;
    float a0x=0, a0y=0, a1x=0, a1y=0;
    for (int j4 = 0; j4 < 128; j4 += 4){
      float4 f0 = *(const float4*)(ga0 + j4);
      float4 f1 = *(const float4*)(ga1 + j4);
      #define JSTEP(F, JI) { \
        float2 wv = *(const float2*)&smem[(j4+JI)*128 + lane*2]; \
        a0x += f0.F*wv.x; a0y += f0.F*wv.y; \
        a1x += f1.F*wv.x; a1y += f1.F*wv.y; }
      JSTEP(x,0) JSTEP(y,1) JSTEP(z,2) JSTEP(w,3)
      #undef JSTEP
    }
    for (int j4 = 0; j4 < 128; j4 += 4){
      float4 h0 = *(const float4*)(gh0 + j4);
      float4 h1 = *(const float4*)(gh1 + j4);
      float4 f0, f1;
      f0.x = geluf(h0.x); f0.y = geluf(h0.y); f0.z = geluf(h0.z); f0.w = geluf(h0.w);
      f1.x = geluf(h1.x); f1.y = geluf(h1.y); f1.z = geluf(h1.z); f1.w = geluf(h1.w);
      #define JSTEP(F, JI) { \
        float2 wv = *(const float2*)&smem[(128+j4+JI)*128 + lane*2]; \
        a0x += f0.F*wv.x; a0y += f0.F*wv.y; \
        a1x += f1.F*wv.x; a1y += f1.F*wv.y; }
      JSTEP(x,0) JSTEP(y,1) JSTEP(z,2) JSTEP(w,3)
      #undef JSTEP
    }
    float2 o0, o1;
    o0.x = a0x + bx; o0.y = a0y + by;
    o1.x = a1x + bx; o1.y = a1y + by;
    *(float2*)(out + (size_t)vp*128 + lane*2) = o0;
    *(float2*)(out + (size_t)(vp+1)*128 + lane*2) = o1;
  }
}

extern "C" void kernel_launch(void* const* d_in, const int* in_sizes, int n_in,
                              void* d_out, int out_size, void* d_ws, size_t ws_size,
                              hipStream_t stream)
{
  (void)in_sizes; (void)n_in; (void)out_size; (void)ws_size;
  const float* X  = (const float*)d_in[0];
  const int*   ei = (const int*)d_in[1];
  const float* W1 = (const float*)d_in[2];
  const float* b1 = (const float*)d_in[3];
  const float* WA = (const float*)d_in[4];
  const float* WB = (const float*)d_in[5];
  const float* W2 = (const float*)d_in[6];
  const float* b2 = (const float*)d_in[7];
  float* out = (float*)d_out;
  const int* src = ei;
  const int* dst = ei + NE;

  char* p = (char*)d_ws;
  float* H    = (float*)(p);               // 25,600,000 B
  float* GA   = (float*)(p + 25600000);    // 25,600,000 B
  float* Wtar = (float*)(p + 51200000);    //  6,400,000 B
  int*   deg  = (int*)(p + 57600000);      //    200,192 B
  int*   cur  = (int*)(p + 57800192);      //    200,192 B
  int*   offs = (int*)(p + 58000384);      //    200,448 B
  int*   elist= (int*)(p + 58200832);      //  1,600,000 B  (total ~59.8 MB)

  (void)hipMemsetAsync(deg, 0, 400384, stream);  // zeroes deg + cur (contiguous)

  (void)hipFuncSetAttribute((const void*)k_ff2, hipFuncAttributeMaxDynamicSharedMemorySize, 131072);

  k_ff1 <<<1024, 256, 65536, stream>>>(X, W1, b1, H);
  k_hist<<<(NE+255)/256, 256, 0, stream>>>(dst, deg);
  k_scan<<<1, 1024, 0, stream>>>(deg, offs);
  k_fill<<<(NE+255)/256, 256, 0, stream>>>(dst, offs, cur, elist);
  k_edge<<<1024, 256, 65536, stream>>>(H, WA, WB, src, Wtar);
  k_agg <<<(NN+3)/4, 256, 0, stream>>>(H, Wtar, src, offs, elist, GA);
  k_ff2 <<<512, 256, 131072, stream>>>(GA, H, W2, b2, out);
}

// Round 4
// 1000.965 us; speedup vs baseline: 1.5118x; 1.5118x over previous
//
#include <hip/hip_runtime.h>
#include <hip/hip_bf16.h>

#define NN 50000
#define NE 400000

__device__ __forceinline__ float geluf(float x){ return 0.5f*x*(1.0f+erff(x*0.70710678118654752440f)); }

// ---------------- K1: H = gelu(X @ W1^T + b1) ----------------
__global__ __launch_bounds__(512) void k_ff1(const float* __restrict__ X,
    const float* __restrict__ W1, const float* __restrict__ b1,
    float* __restrict__ H)
{
  extern __shared__ float smem[]; // [128][128]: smem[k*128+c] = W1[c*128+k]
  for (int j = threadIdx.x; j < 128*128; j += 512){
    int k = j >> 7, c = j & 127;
    smem[j] = W1[c*128 + k];
  }
  __syncthreads();
  const int quarter = threadIdx.x >> 7;   // 0..3
  const int c = threadIdx.x & 127;
  const float bias = b1[c];
  for (int row = blockIdx.x*4 + quarter; row < NN; row += gridDim.x*4){
    const float* xr = X + (size_t)row*128;
    float acc = 0.f;
    #pragma unroll
    for (int k4 = 0; k4 < 128; k4 += 4){
      float4 xv = *(const float4*)(xr + k4);
      acc += xv.x * smem[(k4+0)*128 + c];
      acc += xv.y * smem[(k4+1)*128 + c];
      acc += xv.z * smem[(k4+2)*128 + c];
      acc += xv.w * smem[(k4+3)*128 + c];
    }
    H[(size_t)row*128 + c] = geluf(acc + bias);
  }
}

// ---------------- sort edges by dst: hist -> scan -> fill ----------------
__global__ void k_hist(const int* __restrict__ dst, int* __restrict__ deg){
  int e = blockIdx.x*256 + threadIdx.x;
  if (e < NE) atomicAdd(&deg[dst[e]], 1);
}

__global__ __launch_bounds__(1024) void k_scan(const int* __restrict__ deg, int* __restrict__ offs){
  __shared__ int wsum[16];
  __shared__ int sbase_s;
  const int tid = threadIdx.x, lane = tid & 63, wave = tid >> 6;
  if (tid == 0) sbase_s = 0;
  __syncthreads();
  for (int base = 0; base < NN; base += 4096){
    int i0 = base + tid*4;
    int v0=0,v1=0,v2=0,v3=0;
    if (i0+3 < NN){ int4 v = *(const int4*)(deg+i0); v0=v.x;v1=v.y;v2=v.z;v3=v.w; }
    else {
      if (i0   < NN) v0 = deg[i0];
      if (i0+1 < NN) v1 = deg[i0+1];
      if (i0+2 < NN) v2 = deg[i0+2];
    }
    int own = v0+v1+v2+v3;
    int inc = own;
    #pragma unroll
    for (int s=1;s<64;s<<=1){ int t = __shfl_up(inc, s, 64); if (lane >= s) inc += t; }
    if (lane == 63) wsum[wave] = inc;
    __syncthreads();
    if (wave == 0 && lane < 16){
      int w = wsum[lane];
      #pragma unroll
      for (int s=1;s<16;s<<=1){ int t = __shfl_up(w, s, 64); if (lane >= s) w += t; }
      wsum[lane] = w;
    }
    __syncthreads();
    int sbase = sbase_s;
    int wbase = sbase + (wave ? wsum[wave-1] : 0);
    int excl = wbase + inc - own;
    if (i0   < NN) offs[i0]   = excl;
    if (i0+1 < NN) offs[i0+1] = excl + v0;
    if (i0+2 < NN) offs[i0+2] = excl + v0+v1;
    if (i0+3 < NN) offs[i0+3] = excl + v0+v1+v2;
    __syncthreads();
    if (tid == 0) sbase_s = sbase + wsum[15];
    __syncthreads();
  }
  if (tid == 0) offs[NN] = sbase_s;
}

__global__ void k_fill(const int* __restrict__ dst, const int* __restrict__ offs,
                       int* __restrict__ cur, int* __restrict__ elist){
  int e = blockIdx.x*256 + threadIdx.x;
  if (e < NE){
    int d = dst[e];
    int p = atomicAdd(&cur[d], 1);
    elist[offs[d] + p] = e;
  }
}

// ---------------- K2a: W_tar[e] = gelu(H[src] @ WA^T) @ WB^T ----------------
__global__ __launch_bounds__(512) void k_edge(const float* __restrict__ H,
    const float* __restrict__ WA, const float* __restrict__ WB,
    const int* __restrict__ src, float* __restrict__ Wtar)
{
  extern __shared__ float smem[]; // [128][128]: smem[k*128+h] = WA[h*128+k]
  for (int j = threadIdx.x; j < 128*128; j += 512){
    int k = j >> 7, h = j & 127;
    smem[j] = WA[h*128 + k];
  }
  const int lane = threadIdx.x & 63;
  const int wave = threadIdx.x >> 6;   // 0..7
  float wb0[4], wb1[4];
  #pragma unroll
  for (int m = 0; m < 4; m++){
    wb0[m] = WB[m*128 + lane];
    wb1[m] = WB[m*128 + 64 + lane];
  }
  __syncthreads();
  for (int eb = (blockIdx.x*8 + wave)*4; eb < NE; eb += gridDim.x*32){
    const float* h0 = H + (size_t)src[eb+0]*128;
    const float* h1 = H + (size_t)src[eb+1]*128;
    const float* h2 = H + (size_t)src[eb+2]*128;
    const float* h3 = H + (size_t)src[eb+3]*128;
    float a0x=0,a0y=0,a1x=0,a1y=0,a2x=0,a2y=0,a3x=0,a3y=0;
    for (int k4 = 0; k4 < 128; k4 += 4){
      float4 v0 = *(const float4*)(h0 + k4);
      float4 v1 = *(const float4*)(h1 + k4);
      float4 v2 = *(const float4*)(h2 + k4);
      float4 v3 = *(const float4*)(h3 + k4);
      #define KSTEP(F, KI) { \
        float wa = smem[(k4+KI)*128 + lane]; \
        float wb = smem[(k4+KI)*128 + 64 + lane]; \
        a0x += v0.F*wa; a0y += v0.F*wb; \
        a1x += v1.F*wa; a1y += v1.F*wb; \
        a2x += v2.F*wa; a2y += v2.F*wb; \
        a3x += v3.F*wa; a3y += v3.F*wb; }
      KSTEP(x,0) KSTEP(y,1) KSTEP(z,2) KSTEP(w,3)
      #undef KSTEP
    }
    float t0x = geluf(a0x), t0y = geluf(a0y);
    float t1x = geluf(a1x), t1y = geluf(a1y);
    float t2x = geluf(a2x), t2y = geluf(a2y);
    float t3x = geluf(a3x), t3y = geluf(a3y);
    float r[16];
    #pragma unroll
    for (int m = 0; m < 4; m++){
      r[0*4+m] = t0x*wb0[m] + t0y*wb1[m];
      r[1*4+m] = t1x*wb0[m] + t1y*wb1[m];
      r[2*4+m] = t2x*wb0[m] + t2y*wb1[m];
      r[3*4+m] = t3x*wb0[m] + t3y*wb1[m];
    }
    #pragma unroll
    for (int s = 1; s < 64; s <<= 1){
      #pragma unroll
      for (int q = 0; q < 16; q++)
        r[q] += __shfl_xor(r[q], s, 64);
    }
    float outv = 0.f;
    #pragma unroll
    for (int q = 0; q < 16; q++)
      if (lane == q) outv = r[q];
    if (lane < 16) Wtar[(size_t)eb*4 + lane] = outv;
  }
}

// ------- K2b: per-node register aggregation; GA = gelu(agg_node_mean) -------
__global__ __launch_bounds__(256) void k_agg(const float* __restrict__ H,
    const float* __restrict__ Wtar, const int* __restrict__ src,
    const int* __restrict__ offs, const int* __restrict__ elist,
    float* __restrict__ GA)
{
  const int lane = threadIdx.x & 63;
  const int wave = threadIdx.x >> 6;
  for (int v = blockIdx.x*4 + wave; v < NN; v += gridDim.x*4){
    int e0 = offs[v], e1 = offs[v+1];
    float ax0=0, ax1=0, ax2=0, ax3=0;   // h = 2*lane
    float ay0=0, ay1=0, ay2=0, ay3=0;   // h = 2*lane+1
    float s0=0, s1=0, s2=0, s3=0;
    for (int idx = e0; idx < e1; idx++){
      int e = elist[idx];
      int sn = src[e];
      float2 hv = *(const float2*)(H + (size_t)sn*128 + lane*2);
      float4 wt = *(const float4*)(Wtar + (size_t)e*4);
      ax0 += hv.x*wt.x; ax1 += hv.x*wt.y; ax2 += hv.x*wt.z; ax3 += hv.x*wt.w;
      ay0 += hv.y*wt.x; ay1 += hv.y*wt.y; ay2 += hv.y*wt.z; ay3 += hv.y*wt.w;
      s0 += wt.x; s1 += wt.y; s2 += wt.z; s3 += wt.w;
    }
    float inv = 1.0f / fmaxf((float)(e1 - e0), 1.0f);
    float ox = geluf(ax0)*s0 + geluf(ax1)*s1 + geluf(ax2)*s2 + geluf(ax3)*s3;
    float oy = geluf(ay0)*s0 + geluf(ay1)*s1 + geluf(ay2)*s2 + geluf(ay3)*s3;
    float2 res;
    res.x = geluf(ox * inv);
    res.y = geluf(oy * inv);
    *(float2*)(GA + (size_t)v*128 + lane*2) = res;
  }
}

// ------- K3: out = [GA, gelu(H)] @ W2^T + b2  (column-split, GA pre-gelu'd) -------
__global__ __launch_bounds__(512) void k_ff2(const float* __restrict__ GA,
    const float* __restrict__ H, const float* __restrict__ W2,
    const float* __restrict__ b2, float* __restrict__ out)
{
  extern __shared__ float smem[]; // [256 j][65]: smem[j*65+c] = W2[(cbase+c)*256+j]
  const int half = blockIdx.x & 1;          // which 64 output cols
  const int cbase = half * 64;
  for (int idx = threadIdx.x; idx < 64*256; idx += 512){
    int o = idx >> 8, j = idx & 255;        // coalesced read over j
    smem[j*65 + o] = W2[(size_t)(cbase + o)*256 + j];
  }
  __syncthreads();
  const int lane = threadIdx.x & 63;
  const int wave = threadIdx.x >> 6;        // 0..7
  const float bias = b2[cbase + lane];
  const int qstride = (gridDim.x >> 1) * 8;
  for (int q = (blockIdx.x >> 1)*8 + wave; q < NN/4; q += qstride){
    int row = q*4;
    const float* ga = GA + (size_t)row*128;
    const float* hh = H  + (size_t)row*128;
    float acc0=0, acc1=0, acc2=0, acc3=0;
    for (int j4 = 0; j4 < 128; j4 += 4){
      float4 f0 = *(const float4*)(ga + 0*128 + j4);
      float4 f1 = *(const float4*)(ga + 1*128 + j4);
      float4 f2 = *(const float4*)(ga + 2*128 + j4);
      float4 f3 = *(const float4*)(ga + 3*128 + j4);
      float w0 = smem[(j4+0)*65 + lane];
      float w1 = smem[(j4+1)*65 + lane];
      float w2 = smem[(j4+2)*65 + lane];
      float w3 = smem[(j4+3)*65 + lane];
      acc0 += f0.x*w0 + f0.y*w1 + f0.z*w2 + f0.w*w3;
      acc1 += f1.x*w0 + f1.y*w1 + f1.z*w2 + f1.w*w3;
      acc2 += f2.x*w0 + f2.y*w1 + f2.z*w2 + f2.w*w3;
      acc3 += f3.x*w0 + f3.y*w1 + f3.z*w2 + f3.w*w3;
    }
    for (int j4 = 0; j4 < 128; j4 += 4){
      float4 f0 = *(const float4*)(hh + 0*128 + j4);
      float4 f1 = *(const float4*)(hh + 1*128 + j4);
      float4 f2 = *(const float4*)(hh + 2*128 + j4);
      float4 f3 = *(const float4*)(hh + 3*128 + j4);
      f0.x=geluf(f0.x); f0.y=geluf(f0.y); f0.z=geluf(f0.z); f0.w=geluf(f0.w);
      f1.x=geluf(f1.x); f1.y=geluf(f1.y); f1.z=geluf(f1.z); f1.w=geluf(f1.w);
      f2.x=geluf(f2.x); f2.y=geluf(f2.y); f2.z=geluf(f2.z); f2.w=geluf(f2.w);
      f3.x=geluf(f3.x); f3.y=geluf(f3.y); f3.z=geluf(f3.z); f3.w=geluf(f3.w);
      float w0 = smem[(128+j4+0)*65 + lane];
      float w1 = smem[(128+j4+1)*65 + lane];
      float w2 = smem[(128+j4+2)*65 + lane];
      float w3 = smem[(128+j4+3)*65 + lane];
      acc0 += f0.x*w0 + f0.y*w1 + f0.z*w2 + f0.w*w3;
      acc1 += f1.x*w0 + f1.y*w1 + f1.z*w2 + f1.w*w3;
      acc2 += f2.x*w0 + f2.y*w1 + f2.z*w2 + f2.w*w3;
      acc3 += f3.x*w0 + f3.y*w1 + f3.z*w2 + f3.w*w3;
    }
    out[(size_t)(row+0)*128 + cbase + lane] = acc0 + bias;
    out[(size_t)(row+1)*128 + cbase + lane] = acc1 + bias;
    out[(size_t)(row+2)*128 + cbase + lane] = acc2 + bias;
    out[(size_t)(row+3)*128 + cbase + lane] = acc3 + bias;
  }
}

extern "C" void kernel_launch(void* const* d_in, const int* in_sizes, int n_in,
                              void* d_out, int out_size, void* d_ws, size_t ws_size,
                              hipStream_t stream)
{
  (void)in_sizes; (void)n_in; (void)out_size; (void)ws_size;
  const float* X  = (const float*)d_in[0];
  const int*   ei = (const int*)d_in[1];
  const float* W1 = (const float*)d_in[2];
  const float* b1 = (const float*)d_in[3];
  const float* WA = (const float*)d_in[4];
  const float* WB = (const float*)d_in[5];
  const float* W2 = (const float*)d_in[6];
  const float* b2 = (const float*)d_in[7];
  float* out = (float*)d_out;
  const int* src = ei;
  const int* dst = ei + NE;

  char* p = (char*)d_ws;
  float* H    = (float*)(p);               // 25,600,000 B
  float* GA   = (float*)(p + 25600000);    // 25,600,000 B
  float* Wtar = (float*)(p + 51200000);    //  6,400,000 B
  int*   deg  = (int*)(p + 57600000);      //    200,192 B
  int*   cur  = (int*)(p + 57800192);      //    200,192 B
  int*   offs = (int*)(p + 58000384);      //    200,448 B
  int*   elist= (int*)(p + 58200832);      //  1,600,000 B  (total ~59.8 MB)

  (void)hipMemsetAsync(deg, 0, 400384, stream);  // zeroes deg + cur (contiguous)

  (void)hipFuncSetAttribute((const void*)k_ff2, hipFuncAttributeMaxDynamicSharedMemorySize, 256*65*4);

  k_ff1 <<<1024, 512, 65536, stream>>>(X, W1, b1, H);
  k_hist<<<(NE+255)/256, 256, 0, stream>>>(dst, deg);
  k_scan<<<1, 1024, 0, stream>>>(deg, offs);
  k_fill<<<(NE+255)/256, 256, 0, stream>>>(dst, offs, cur, elist);
  k_edge<<<512, 512, 65536, stream>>>(H, WA, WB, src, Wtar);
  k_agg <<<(NN+3)/4, 256, 0, stream>>>(H, Wtar, src, offs, elist, GA);
  k_ff2 <<<1024, 512, 256*65*4, stream>>>(GA, H, W2, b2, out);
}

// Round 5
// 605.967 us; speedup vs baseline: 2.4972x; 1.6518x over previous
//
#include <hip/hip_runtime.h>
#include <hip/hip_bf16.h>

#define NN 50000
#define NE 400000

__device__ __forceinline__ float geluf(float x){ return 0.5f*x*(1.0f+erff(x*0.70710678118654752440f)); }

// ---- K1: H = gelu(X @ W1^T + b1). wave=4 rows, lane=cols (lane, lane+64) ----
__global__ __launch_bounds__(512) void k_ff1(const float* __restrict__ X,
    const float* __restrict__ W1, const float* __restrict__ b1,
    float* __restrict__ H)
{
  extern __shared__ float smem[]; // smem[k*128+c] = W1[c*128+k]
  for (int j = threadIdx.x; j < 128*128; j += 512){
    int k = j >> 7, c = j & 127;
    smem[j] = W1[c*128 + k];
  }
  __syncthreads();
  const int lane = threadIdx.x & 63;
  const int wave = threadIdx.x >> 6;  // 0..7
  const float blo = b1[lane], bhi = b1[lane+64];
  for (int base = (blockIdx.x*8 + wave)*4; base < NN; base += gridDim.x*32){
    const float* x0 = X + (size_t)(base+0)*128;
    const float* x1 = X + (size_t)(base+1)*128;
    const float* x2 = X + (size_t)(base+2)*128;
    const float* x3 = X + (size_t)(base+3)*128;
    float a0x=0,a0y=0,a1x=0,a1y=0,a2x=0,a2y=0,a3x=0,a3y=0;
    for (int k4 = 0; k4 < 128; k4 += 4){
      float4 v0 = *(const float4*)(x0 + k4);
      float4 v1 = *(const float4*)(x1 + k4);
      float4 v2 = *(const float4*)(x2 + k4);
      float4 v3 = *(const float4*)(x3 + k4);
      #define KSTEP(F, KI) { \
        float wa = smem[(k4+KI)*128 + lane]; \
        float wb = smem[(k4+KI)*128 + 64 + lane]; \
        a0x += v0.F*wa; a0y += v0.F*wb; \
        a1x += v1.F*wa; a1y += v1.F*wb; \
        a2x += v2.F*wa; a2y += v2.F*wb; \
        a3x += v3.F*wa; a3y += v3.F*wb; }
      KSTEP(x,0) KSTEP(y,1) KSTEP(z,2) KSTEP(w,3)
      #undef KSTEP
    }
    H[(size_t)(base+0)*128 + lane]    = geluf(a0x + blo);
    H[(size_t)(base+0)*128 + 64+lane] = geluf(a0y + bhi);
    H[(size_t)(base+1)*128 + lane]    = geluf(a1x + blo);
    H[(size_t)(base+1)*128 + 64+lane] = geluf(a1y + bhi);
    H[(size_t)(base+2)*128 + lane]    = geluf(a2x + blo);
    H[(size_t)(base+2)*128 + 64+lane] = geluf(a2y + bhi);
    H[(size_t)(base+3)*128 + lane]    = geluf(a3x + blo);
    H[(size_t)(base+3)*128 + 64+lane] = geluf(a3y + bhi);
  }
}

// ---------------- sort edges by dst: hist -> scan -> fill(src) ----------------
__global__ void k_hist(const int* __restrict__ dst, int* __restrict__ deg){
  int e = blockIdx.x*256 + threadIdx.x;
  if (e < NE) atomicAdd(&deg[dst[e]], 1);
}

__global__ __launch_bounds__(1024) void k_scan(const int* __restrict__ deg, int* __restrict__ offs){
  __shared__ int wsum[16];
  __shared__ int sbase_s;
  const int tid = threadIdx.x, lane = tid & 63, wave = tid >> 6;
  if (tid == 0) sbase_s = 0;
  __syncthreads();
  for (int base = 0; base < NN; base += 4096){
    int i0 = base + tid*4;
    int v0=0,v1=0,v2=0,v3=0;
    if (i0+3 < NN){ int4 v = *(const int4*)(deg+i0); v0=v.x;v1=v.y;v2=v.z;v3=v.w; }
    else {
      if (i0   < NN) v0 = deg[i0];
      if (i0+1 < NN) v1 = deg[i0+1];
      if (i0+2 < NN) v2 = deg[i0+2];
    }
    int own = v0+v1+v2+v3;
    int inc = own;
    #pragma unroll
    for (int s=1;s<64;s<<=1){ int t = __shfl_up(inc, s, 64); if (lane >= s) inc += t; }
    if (lane == 63) wsum[wave] = inc;
    __syncthreads();
    if (wave == 0 && lane < 16){
      int w = wsum[lane];
      #pragma unroll
      for (int s=1;s<16;s<<=1){ int t = __shfl_up(w, s, 64); if (lane >= s) w += t; }
      wsum[lane] = w;
    }
    __syncthreads();
    int sbase = sbase_s;
    int wbase = sbase + (wave ? wsum[wave-1] : 0);
    int excl = wbase + inc - own;
    if (i0   < NN) offs[i0]   = excl;
    if (i0+1 < NN) offs[i0+1] = excl + v0;
    if (i0+2 < NN) offs[i0+2] = excl + v0+v1;
    if (i0+3 < NN) offs[i0+3] = excl + v0+v1+v2;
    __syncthreads();
    if (tid == 0) sbase_s = sbase + wsum[15];
    __syncthreads();
  }
  if (tid == 0) offs[NN] = sbase_s;
}

// store SRC node id sorted by dst (removes one indirection in k_agg)
__global__ void k_fill(const int* __restrict__ src, const int* __restrict__ dst,
                       const int* __restrict__ offs, int* __restrict__ cur,
                       int* __restrict__ slist){
  int e = blockIdx.x*256 + threadIdx.x;
  if (e < NE){
    int d = dst[e];
    int p = atomicAdd(&cur[d], 1);
    slist[offs[d] + p] = src[e];
  }
}

// ---- K2a: per-NODE T[v] = gelu(H[v] @ WA^T) @ WB^T  (8x less work than per-edge) ----
__global__ __launch_bounds__(512) void k_node(const float* __restrict__ H,
    const float* __restrict__ WA, const float* __restrict__ WB,
    float* __restrict__ T)
{
  extern __shared__ float smem[]; // smem[k*128+h] = WA[h*128+k]
  for (int j = threadIdx.x; j < 128*128; j += 512){
    int k = j >> 7, h = j & 127;
    smem[j] = WA[h*128 + k];
  }
  const int lane = threadIdx.x & 63;
  const int wave = threadIdx.x >> 6;   // 0..7
  float wb0[4], wb1[4];
  #pragma unroll
  for (int m = 0; m < 4; m++){
    wb0[m] = WB[m*128 + lane];
    wb1[m] = WB[m*128 + 64 + lane];
  }
  __syncthreads();
  for (int base = (blockIdx.x*8 + wave)*4; base < NN; base += gridDim.x*32){
    const float* h0 = H + (size_t)(base+0)*128;
    const float* h1 = H + (size_t)(base+1)*128;
    const float* h2 = H + (size_t)(base+2)*128;
    const float* h3 = H + (size_t)(base+3)*128;
    float a0x=0,a0y=0,a1x=0,a1y=0,a2x=0,a2y=0,a3x=0,a3y=0;
    for (int k4 = 0; k4 < 128; k4 += 4){
      float4 v0 = *(const float4*)(h0 + k4);
      float4 v1 = *(const float4*)(h1 + k4);
      float4 v2 = *(const float4*)(h2 + k4);
      float4 v3 = *(const float4*)(h3 + k4);
      #define KSTEP(F, KI) { \
        float wa = smem[(k4+KI)*128 + lane]; \
        float wb = smem[(k4+KI)*128 + 64 + lane]; \
        a0x += v0.F*wa; a0y += v0.F*wb; \
        a1x += v1.F*wa; a1y += v1.F*wb; \
        a2x += v2.F*wa; a2y += v2.F*wb; \
        a3x += v3.F*wa; a3y += v3.F*wb; }
      KSTEP(x,0) KSTEP(y,1) KSTEP(z,2) KSTEP(w,3)
      #undef KSTEP
    }
    float t0x = geluf(a0x), t0y = geluf(a0y);
    float t1x = geluf(a1x), t1y = geluf(a1y);
    float t2x = geluf(a2x), t2y = geluf(a2y);
    float t3x = geluf(a3x), t3y = geluf(a3y);
    float r[16];
    #pragma unroll
    for (int m = 0; m < 4; m++){
      r[0*4+m] = t0x*wb0[m] + t0y*wb1[m];
      r[1*4+m] = t1x*wb0[m] + t1y*wb1[m];
      r[2*4+m] = t2x*wb0[m] + t2y*wb1[m];
      r[3*4+m] = t3x*wb0[m] + t3y*wb1[m];
    }
    #pragma unroll
    for (int s = 1; s < 64; s <<= 1){
      #pragma unroll
      for (int q = 0; q < 16; q++)
        r[q] += __shfl_xor(r[q], s, 64);
    }
    float outv = 0.f;
    #pragma unroll
    for (int q = 0; q < 16; q++)
      if (lane == q) outv = r[q];
    if (lane < 16) T[(size_t)base*4 + lane] = outv;
  }
}

// ------- K2b: per-node aggregation; GA = gelu( (Σ_m gelu(Σ_e H_s T_s[m]) · Σ_e T_s[m]) / deg ) -------
__global__ __launch_bounds__(256) void k_agg(const float* __restrict__ H,
    const float* __restrict__ T, const int* __restrict__ offs,
    const int* __restrict__ slist, float* __restrict__ GA)
{
  const int lane = threadIdx.x & 63;
  const int wave = threadIdx.x >> 6;
  for (int v = blockIdx.x*4 + wave; v < NN; v += gridDim.x*4){
    int e0 = offs[v], e1 = offs[v+1];
    float ax0=0, ax1=0, ax2=0, ax3=0;   // h = 2*lane
    float ay0=0, ay1=0, ay2=0, ay3=0;   // h = 2*lane+1
    float s0=0, s1=0, s2=0, s3=0;
    for (int idx = e0; idx < e1; idx++){
      int sn = slist[idx];
      float2 hv = *(const float2*)(H + (size_t)sn*128 + lane*2);
      float4 wt = *(const float4*)(T + (size_t)sn*4);
      ax0 += hv.x*wt.x; ax1 += hv.x*wt.y; ax2 += hv.x*wt.z; ax3 += hv.x*wt.w;
      ay0 += hv.y*wt.x; ay1 += hv.y*wt.y; ay2 += hv.y*wt.z; ay3 += hv.y*wt.w;
      s0 += wt.x; s1 += wt.y; s2 += wt.z; s3 += wt.w;
    }
    float inv = 1.0f / fmaxf((float)(e1 - e0), 1.0f);
    float ox = geluf(ax0)*s0 + geluf(ax1)*s1 + geluf(ax2)*s2 + geluf(ax3)*s3;
    float oy = geluf(ay0)*s0 + geluf(ay1)*s1 + geluf(ay2)*s2 + geluf(ay3)*s3;
    float2 res;
    res.x = geluf(ox * inv);
    res.y = geluf(oy * inv);
    *(float2*)(GA + (size_t)v*128 + lane*2) = res;
  }
}

// ------- K3: out = [GA, gelu(H)] @ W2^T + b2  (column-split, GA pre-gelu'd) -------
__global__ __launch_bounds__(512) void k_ff2(const float* __restrict__ GA,
    const float* __restrict__ H, const float* __restrict__ W2,
    const float* __restrict__ b2, float* __restrict__ out)
{
  extern __shared__ float smem[]; // [256 j][65]: smem[j*65+c] = W2[(cbase+c)*256+j]
  const int half = blockIdx.x & 1;
  const int cbase = half * 64;
  for (int idx = threadIdx.x; idx < 64*256; idx += 512){
    int o = idx >> 8, j = idx & 255;
    smem[j*65 + o] = W2[(size_t)(cbase + o)*256 + j];
  }
  __syncthreads();
  const int lane = threadIdx.x & 63;
  const int wave = threadIdx.x >> 6;
  const float bias = b2[cbase + lane];
  const int qstride = (gridDim.x >> 1) * 8;
  for (int q = (blockIdx.x >> 1)*8 + wave; q < NN/4; q += qstride){
    int row = q*4;
    const float* ga = GA + (size_t)row*128;
    const float* hh = H  + (size_t)row*128;
    float acc0=0, acc1=0, acc2=0, acc3=0;
    for (int j4 = 0; j4 < 128; j4 += 4){
      float4 f0 = *(const float4*)(ga + 0*128 + j4);
      float4 f1 = *(const float4*)(ga + 1*128 + j4);
      float4 f2 = *(const float4*)(ga + 2*128 + j4);
      float4 f3 = *(const float4*)(ga + 3*128 + j4);
      float w0 = smem[(j4+0)*65 + lane];
      float w1 = smem[(j4+1)*65 + lane];
      float w2 = smem[(j4+2)*65 + lane];
      float w3 = smem[(j4+3)*65 + lane];
      acc0 += f0.x*w0 + f0.y*w1 + f0.z*w2 + f0.w*w3;
      acc1 += f1.x*w0 + f1.y*w1 + f1.z*w2 + f1.w*w3;
      acc2 += f2.x*w0 + f2.y*w1 + f2.z*w2 + f2.w*w3;
      acc3 += f3.x*w0 + f3.y*w1 + f3.z*w2 + f3.w*w3;
    }
    for (int j4 = 0; j4 < 128; j4 += 4){
      float4 f0 = *(const float4*)(hh + 0*128 + j4);
      float4 f1 = *(const float4*)(hh + 1*128 + j4);
      float4 f2 = *(const float4*)(hh + 2*128 + j4);
      float4 f3 = *(const float4*)(hh + 3*128 + j4);
      f0.x=geluf(f0.x); f0.y=geluf(f0.y); f0.z=geluf(f0.z); f0.w=geluf(f0.w);
      f1.x=geluf(f1.x); f1.y=geluf(f1.y); f1.z=geluf(f1.z); f1.w=geluf(f1.w);
      f2.x=geluf(f2.x); f2.y=geluf(f2.y); f2.z=geluf(f2.z); f2.w=geluf(f2.w);
      f3.x=geluf(f3.x); f3.y=geluf(f3.y); f3.z=geluf(f3.z); f3.w=geluf(f3.w);
      float w0 = smem[(128+j4+0)*65 + lane];
      float w1 = smem[(128+j4+1)*65 + lane];
      float w2 = smem[(128+j4+2)*65 + lane];
      float w3 = smem[(128+j4+3)*65 + lane];
      acc0 += f0.x*w0 + f0.y*w1 + f0.z*w2 + f0.w*w3;
      acc1 += f1.x*w0 + f1.y*w1 + f1.z*w2 + f1.w*w3;
      acc2 += f2.x*w0 + f2.y*w1 + f2.z*w2 + f2.w*w3;
      acc3 += f3.x*w0 + f3.y*w1 + f3.z*w2 + f3.w*w3;
    }
    out[(size_t)(row+0)*128 + cbase + lane] = acc0 + bias;
    out[(size_t)(row+1)*128 + cbase + lane] = acc1 + bias;
    out[(size_t)(row+2)*128 + cbase + lane] = acc2 + bias;
    out[(size_t)(row+3)*128 + cbase + lane] = acc3 + bias;
  }
}

extern "C" void kernel_launch(void* const* d_in, const int* in_sizes, int n_in,
                              void* d_out, int out_size, void* d_ws, size_t ws_size,
                              hipStream_t stream)
{
  (void)in_sizes; (void)n_in; (void)out_size; (void)ws_size;
  const float* X  = (const float*)d_in[0];
  const int*   ei = (const int*)d_in[1];
  const float* W1 = (const float*)d_in[2];
  const float* b1 = (const float*)d_in[3];
  const float* WA = (const float*)d_in[4];
  const float* WB = (const float*)d_in[5];
  const float* W2 = (const float*)d_in[6];
  const float* b2 = (const float*)d_in[7];
  float* out = (float*)d_out;
  const int* src = ei;
  const int* dst = ei + NE;

  char* p = (char*)d_ws;
  float* H    = (float*)(p);               // 25,600,000 B
  float* GA   = (float*)(p + 25600000);    // 25,600,000 B
  float* T    = (float*)(p + 51200000);    //    800,000 B
  int*   deg  = (int*)(p + 52000000);      //    200,192 B
  int*   cur  = (int*)(p + 52200192);      //    200,192 B
  int*   offs = (int*)(p + 52400384);      //    200,448 B
  int*   slist= (int*)(p + 52600832);      //  1,600,000 B  (total ~54.2 MB)

  (void)hipMemsetAsync(deg, 0, 400384, stream);  // zeroes deg + cur (contiguous)

  (void)hipFuncSetAttribute((const void*)k_ff2, hipFuncAttributeMaxDynamicSharedMemorySize, 256*65*4);

  k_ff1 <<<512, 512, 65536, stream>>>(X, W1, b1, H);
  k_hist<<<(NE+255)/256, 256, 0, stream>>>(dst, deg);
  k_scan<<<1, 1024, 0, stream>>>(deg, offs);
  k_fill<<<(NE+255)/256, 256, 0, stream>>>(src, dst, offs, cur, slist);
  k_node<<<512, 512, 65536, stream>>>(H, WA, WB, T);
  k_agg <<<(NN+3)/4, 256, 0, stream>>>(H, T, offs, slist, GA);
  k_ff2 <<<1024, 512, 256*65*4, stream>>>(GA, H, W2, b2, out);
}

// Round 6
// 470.831 us; speedup vs baseline: 3.2140x; 1.2870x over previous
//
#include <hip/hip_runtime.h>
#include <hip/hip_bf16.h>

#define NN 50000
#define NE 400000

__device__ __forceinline__ float geluf(float x){ return 0.5f*x*(1.0f+erff(x*0.70710678118654752440f)); }

// ---- K1: H = gelu(X @ W1^T + b1); GH = gelu(H) ----
__global__ __launch_bounds__(512) void k_ff1(const float* __restrict__ X,
    const float* __restrict__ W1, const float* __restrict__ b1,
    float* __restrict__ H, float* __restrict__ GH)
{
  extern __shared__ float smem[]; // smem[k*128+c] = W1[c*128+k]
  for (int j = threadIdx.x; j < 128*128; j += 512){
    int k = j >> 7, c = j & 127;
    smem[j] = W1[c*128 + k];
  }
  __syncthreads();
  const int lane = threadIdx.x & 63;
  const int wave = threadIdx.x >> 6;  // 0..7
  const float blo = b1[lane], bhi = b1[lane+64];
  for (int base = (blockIdx.x*8 + wave)*4; base < NN; base += gridDim.x*32){
    const float* x0 = X + (size_t)(base+0)*128;
    const float* x1 = X + (size_t)(base+1)*128;
    const float* x2 = X + (size_t)(base+2)*128;
    const float* x3 = X + (size_t)(base+3)*128;
    float a0x=0,a0y=0,a1x=0,a1y=0,a2x=0,a2y=0,a3x=0,a3y=0;
    for (int k4 = 0; k4 < 128; k4 += 4){
      float4 v0 = *(const float4*)(x0 + k4);
      float4 v1 = *(const float4*)(x1 + k4);
      float4 v2 = *(const float4*)(x2 + k4);
      float4 v3 = *(const float4*)(x3 + k4);
      #define KSTEP(F, KI) { \
        float wa = smem[(k4+KI)*128 + lane]; \
        float wb = smem[(k4+KI)*128 + 64 + lane]; \
        a0x += v0.F*wa; a0y += v0.F*wb; \
        a1x += v1.F*wa; a1y += v1.F*wb; \
        a2x += v2.F*wa; a2y += v2.F*wb; \
        a3x += v3.F*wa; a3y += v3.F*wb; }
      KSTEP(x,0) KSTEP(y,1) KSTEP(z,2) KSTEP(w,3)
      #undef KSTEP
    }
    float h;
    h = geluf(a0x + blo); H[(size_t)(base+0)*128 + lane]    = h; GH[(size_t)(base+0)*128 + lane]    = geluf(h);
    h = geluf(a0y + bhi); H[(size_t)(base+0)*128 + 64+lane] = h; GH[(size_t)(base+0)*128 + 64+lane] = geluf(h);
    h = geluf(a1x + blo); H[(size_t)(base+1)*128 + lane]    = h; GH[(size_t)(base+1)*128 + lane]    = geluf(h);
    h = geluf(a1y + bhi); H[(size_t)(base+1)*128 + 64+lane] = h; GH[(size_t)(base+1)*128 + 64+lane] = geluf(h);
    h = geluf(a2x + blo); H[(size_t)(base+2)*128 + lane]    = h; GH[(size_t)(base+2)*128 + lane]    = geluf(h);
    h = geluf(a2y + bhi); H[(size_t)(base+2)*128 + 64+lane] = h; GH[(size_t)(base+2)*128 + 64+lane] = geluf(h);
    h = geluf(a3x + blo); H[(size_t)(base+3)*128 + lane]    = h; GH[(size_t)(base+3)*128 + lane]    = geluf(h);
    h = geluf(a3y + bhi); H[(size_t)(base+3)*128 + 64+lane] = h; GH[(size_t)(base+3)*128 + 64+lane] = geluf(h);
  }
}

// ---------------- sort edges by dst: hist -> scan -> fill(src) ----------------
__global__ void k_hist(const int* __restrict__ dst, int* __restrict__ deg){
  int e = blockIdx.x*256 + threadIdx.x;
  if (e < NE) atomicAdd(&deg[dst[e]], 1);
}

__global__ __launch_bounds__(1024) void k_scan(const int* __restrict__ deg, int* __restrict__ offs){
  __shared__ int wsum[16];
  __shared__ int sbase_s;
  const int tid = threadIdx.x, lane = tid & 63, wave = tid >> 6;
  if (tid == 0) sbase_s = 0;
  __syncthreads();
  for (int base = 0; base < NN; base += 4096){
    int i0 = base + tid*4;
    int v0=0,v1=0,v2=0,v3=0;
    if (i0+3 < NN){ int4 v = *(const int4*)(deg+i0); v0=v.x;v1=v.y;v2=v.z;v3=v.w; }
    else {
      if (i0   < NN) v0 = deg[i0];
      if (i0+1 < NN) v1 = deg[i0+1];
      if (i0+2 < NN) v2 = deg[i0+2];
    }
    int own = v0+v1+v2+v3;
    int inc = own;
    #pragma unroll
    for (int s=1;s<64;s<<=1){ int t = __shfl_up(inc, s, 64); if (lane >= s) inc += t; }
    if (lane == 63) wsum[wave] = inc;
    __syncthreads();
    if (wave == 0 && lane < 16){
      int w = wsum[lane];
      #pragma unroll
      for (int s=1;s<16;s<<=1){ int t = __shfl_up(w, s, 64); if (lane >= s) w += t; }
      wsum[lane] = w;
    }
    __syncthreads();
    int sbase = sbase_s;
    int wbase = sbase + (wave ? wsum[wave-1] : 0);
    int excl = wbase + inc - own;
    if (i0   < NN) offs[i0]   = excl;
    if (i0+1 < NN) offs[i0+1] = excl + v0;
    if (i0+2 < NN) offs[i0+2] = excl + v0+v1;
    if (i0+3 < NN) offs[i0+3] = excl + v0+v1+v2;
    __syncthreads();
    if (tid == 0) sbase_s = sbase + wsum[15];
    __syncthreads();
  }
  if (tid == 0) offs[NN] = sbase_s;
}

// store SRC node id sorted by dst (removes one indirection in k_agg)
__global__ void k_fill(const int* __restrict__ src, const int* __restrict__ dst,
                       const int* __restrict__ offs, int* __restrict__ cur,
                       int* __restrict__ slist){
  int e = blockIdx.x*256 + threadIdx.x;
  if (e < NE){
    int d = dst[e];
    int p = atomicAdd(&cur[d], 1);
    slist[offs[d] + p] = src[e];
  }
}

// ---- K2a: per-NODE T[v] = gelu(H[v] @ WA^T) @ WB^T ----
__global__ __launch_bounds__(512) void k_node(const float* __restrict__ H,
    const float* __restrict__ WA, const float* __restrict__ WB,
    float* __restrict__ T)
{
  extern __shared__ float smem[]; // smem[k*128+h] = WA[h*128+k]
  for (int j = threadIdx.x; j < 128*128; j += 512){
    int k = j >> 7, h = j & 127;
    smem[j] = WA[h*128 + k];
  }
  const int lane = threadIdx.x & 63;
  const int wave = threadIdx.x >> 6;   // 0..7
  float wb0[4], wb1[4];
  #pragma unroll
  for (int m = 0; m < 4; m++){
    wb0[m] = WB[m*128 + lane];
    wb1[m] = WB[m*128 + 64 + lane];
  }
  __syncthreads();
  for (int base = (blockIdx.x*8 + wave)*4; base < NN; base += gridDim.x*32){
    const float* h0 = H + (size_t)(base+0)*128;
    const float* h1 = H + (size_t)(base+1)*128;
    const float* h2 = H + (size_t)(base+2)*128;
    const float* h3 = H + (size_t)(base+3)*128;
    float a0x=0,a0y=0,a1x=0,a1y=0,a2x=0,a2y=0,a3x=0,a3y=0;
    for (int k4 = 0; k4 < 128; k4 += 4){
      float4 v0 = *(const float4*)(h0 + k4);
      float4 v1 = *(const float4*)(h1 + k4);
      float4 v2 = *(const float4*)(h2 + k4);
      float4 v3 = *(const float4*)(h3 + k4);
      #define KSTEP(F, KI) { \
        float wa = smem[(k4+KI)*128 + lane]; \
        float wb = smem[(k4+KI)*128 + 64 + lane]; \
        a0x += v0.F*wa; a0y += v0.F*wb; \
        a1x += v1.F*wa; a1y += v1.F*wb; \
        a2x += v2.F*wa; a2y += v2.F*wb; \
        a3x += v3.F*wa; a3y += v3.F*wb; }
      KSTEP(x,0) KSTEP(y,1) KSTEP(z,2) KSTEP(w,3)
      #undef KSTEP
    }
    float t0x = geluf(a0x), t0y = geluf(a0y);
    float t1x = geluf(a1x), t1y = geluf(a1y);
    float t2x = geluf(a2x), t2y = geluf(a2y);
    float t3x = geluf(a3x), t3y = geluf(a3y);
    float r[16];
    #pragma unroll
    for (int m = 0; m < 4; m++){
      r[0*4+m] = t0x*wb0[m] + t0y*wb1[m];
      r[1*4+m] = t1x*wb0[m] + t1y*wb1[m];
      r[2*4+m] = t2x*wb0[m] + t2y*wb1[m];
      r[3*4+m] = t3x*wb0[m] + t3y*wb1[m];
    }
    #pragma unroll
    for (int s = 1; s < 64; s <<= 1){
      #pragma unroll
      for (int q = 0; q < 16; q++)
        r[q] += __shfl_xor(r[q], s, 64);
    }
    float outv = 0.f;
    #pragma unroll
    for (int q = 0; q < 16; q++)
      if (lane == q) outv = r[q];
    if (lane < 16) T[(size_t)base*4 + lane] = outv;
  }
}

// ------- K2b: per-node aggregation; GA = gelu(mean over dst edges) -------
__global__ __launch_bounds__(256) void k_agg(const float* __restrict__ H,
    const float* __restrict__ T, const int* __restrict__ offs,
    const int* __restrict__ slist, float* __restrict__ GA)
{
  const int lane = threadIdx.x & 63;
  const int wave = threadIdx.x >> 6;
  for (int v = blockIdx.x*4 + wave; v < NN; v += gridDim.x*4){
    int e0 = offs[v], e1 = offs[v+1];
    float ax0=0, ax1=0, ax2=0, ax3=0;   // h = 2*lane
    float ay0=0, ay1=0, ay2=0, ay3=0;   // h = 2*lane+1
    float s0=0, s1=0, s2=0, s3=0;
    for (int idx = e0; idx < e1; idx++){
      int sn = slist[idx];
      float2 hv = *(const float2*)(H + (size_t)sn*128 + lane*2);
      float4 wt = *(const float4*)(T + (size_t)sn*4);
      ax0 += hv.x*wt.x; ax1 += hv.x*wt.y; ax2 += hv.x*wt.z; ax3 += hv.x*wt.w;
      ay0 += hv.y*wt.x; ay1 += hv.y*wt.y; ay2 += hv.y*wt.z; ay3 += hv.y*wt.w;
      s0 += wt.x; s1 += wt.y; s2 += wt.z; s3 += wt.w;
    }
    float inv = 1.0f / fmaxf((float)(e1 - e0), 1.0f);
    float ox = geluf(ax0)*s0 + geluf(ax1)*s1 + geluf(ax2)*s2 + geluf(ax3)*s3;
    float oy = geluf(ay0)*s0 + geluf(ay1)*s1 + geluf(ay2)*s2 + geluf(ay3)*s3;
    float2 res;
    res.x = geluf(ox * inv);
    res.y = geluf(oy * inv);
    *(float2*)(GA + (size_t)v*128 + lane*2) = res;
  }
}

// ------- K3: out = [GA, GH] @ W2^T + b2  (column-split; both pre-gelu'd) -------
__global__ __launch_bounds__(512) void k_ff2(const float* __restrict__ GA,
    const float* __restrict__ GH, const float* __restrict__ W2,
    const float* __restrict__ b2, float* __restrict__ out)
{
  extern __shared__ float smem[]; // [256 j][65]: smem[j*65+c] = W2[(cbase+c)*256+j]
  const int half = blockIdx.x & 1;
  const int cbase = half * 64;
  for (int idx = threadIdx.x; idx < 64*256; idx += 512){
    int o = idx >> 8, j = idx & 255;
    smem[j*65 + o] = W2[(size_t)(cbase + o)*256 + j];
  }
  __syncthreads();
  const int lane = threadIdx.x & 63;
  const int wave = threadIdx.x >> 6;
  const float bias = b2[cbase + lane];
  const int qstride = (gridDim.x >> 1) * 8;
  for (int q = (blockIdx.x >> 1)*8 + wave; q < NN/4; q += qstride){
    int row = q*4;
    const float* ga = GA + (size_t)row*128;
    const float* hh = GH + (size_t)row*128;
    float acc0=0, acc1=0, acc2=0, acc3=0;
    for (int j4 = 0; j4 < 128; j4 += 4){
      float4 f0 = *(const float4*)(ga + 0*128 + j4);
      float4 f1 = *(const float4*)(ga + 1*128 + j4);
      float4 f2 = *(const float4*)(ga + 2*128 + j4);
      float4 f3 = *(const float4*)(ga + 3*128 + j4);
      float w0 = smem[(j4+0)*65 + lane];
      float w1 = smem[(j4+1)*65 + lane];
      float w2 = smem[(j4+2)*65 + lane];
      float w3 = smem[(j4+3)*65 + lane];
      acc0 += f0.x*w0 + f0.y*w1 + f0.z*w2 + f0.w*w3;
      acc1 += f1.x*w0 + f1.y*w1 + f1.z*w2 + f1.w*w3;
      acc2 += f2.x*w0 + f2.y*w1 + f2.z*w2 + f2.w*w3;
      acc3 += f3.x*w0 + f3.y*w1 + f3.z*w2 + f3.w*w3;
    }
    for (int j4 = 0; j4 < 128; j4 += 4){
      float4 f0 = *(const float4*)(hh + 0*128 + j4);
      float4 f1 = *(const float4*)(hh + 1*128 + j4);
      float4 f2 = *(const float4*)(hh + 2*128 + j4);
      float4 f3 = *(const float4*)(hh + 3*128 + j4);
      float w0 = smem[(128+j4+0)*65 + lane];
      float w1 = smem[(128+j4+1)*65 + lane];
      float w2 = smem[(128+j4+2)*65 + lane];
      float w3 = smem[(128+j4+3)*65 + lane];
      acc0 += f0.x*w0 + f0.y*w1 + f0.z*w2 + f0.w*w3;
      acc1 += f1.x*w0 + f1.y*w1 + f1.z*w2 + f1.w*w3;
      acc2 += f2.x*w0 + f2.y*w1 + f2.z*w2 + f2.w*w3;
      acc3 += f3.x*w0 + f3.y*w1 + f3.z*w2 + f3.w*w3;
    }
    out[(size_t)(row+0)*128 + cbase + lane] = acc0 + bias;
    out[(size_t)(row+1)*128 + cbase + lane] = acc1 + bias;
    out[(size_t)(row+2)*128 + cbase + lane] = acc2 + bias;
    out[(size_t)(row+3)*128 + cbase + lane] = acc3 + bias;
  }
}

extern "C" void kernel_launch(void* const* d_in, const int* in_sizes, int n_in,
                              void* d_out, int out_size, void* d_ws, size_t ws_size,
                              hipStream_t stream)
{
  (void)in_sizes; (void)n_in; (void)out_size; (void)ws_size;
  const float* X  = (const float*)d_in[0];
  const int*   ei = (const int*)d_in[1];
  const float* W1 = (const float*)d_in[2];
  const float* b1 = (const float*)d_in[3];
  const float* WA = (const float*)d_in[4];
  const float* WB = (const float*)d_in[5];
  const float* W2 = (const float*)d_in[6];
  const float* b2 = (const float*)d_in[7];
  float* out = (float*)d_out;
  const int* src = ei;
  const int* dst = ei + NE;

  char* p = (char*)d_ws;
  float* H    = (float*)(p);               // 25,600,000 B
  float* GH   = (float*)(p + 25600000);    // 25,600,000 B
  float* GA   = (float*)(p + 51200000);    // 25,600,000 B
  float* T    = (float*)(p + 76800000);    //    800,000 B
  int*   deg  = (int*)(p + 77600000);      //    200,192 B
  int*   cur  = (int*)(p + 77800192);      //    200,192 B
  int*   offs = (int*)(p + 78000384);      //    200,448 B
  int*   slist= (int*)(p + 78200832);      //  1,600,000 B  (total ~79.8 MB)

  (void)hipMemsetAsync(deg, 0, 400384, stream);  // zeroes deg + cur (contiguous)

  (void)hipFuncSetAttribute((const void*)k_ff2, hipFuncAttributeMaxDynamicSharedMemorySize, 256*65*4);

  k_ff1 <<<512, 512, 65536, stream>>>(X, W1, b1, H, GH);
  k_hist<<<(NE+255)/256, 256, 0, stream>>>(dst, deg);
  k_scan<<<1, 1024, 0, stream>>>(deg, offs);
  k_fill<<<(NE+255)/256, 256, 0, stream>>>(src, dst, offs, cur, slist);
  k_node<<<512, 512, 65536, stream>>>(H, WA, WB, T);
  k_agg <<<(NN+3)/4, 256, 0, stream>>>(H, T, offs, slist, GA);
  k_ff2 <<<1024, 512, 256*65*4, stream>>>(GA, GH, W2, b2, out);
}

// Round 7
// 319.956 us; speedup vs baseline: 4.7295x; 1.4715x over previous
//
#include <hip/hip_runtime.h>
#include <hip/hip_bf16.h>

#define NN 50000
#define NE 400000

typedef unsigned short u16;
typedef short short8 __attribute__((ext_vector_type(8)));
typedef float f32x4 __attribute__((ext_vector_type(4)));

__device__ __forceinline__ float geluf(float x){ return 0.5f*x*(1.0f+erff(x*0.70710678118654752440f)); }
__device__ __forceinline__ u16 f2bfb(float f){
  union { __hip_bfloat16 h; u16 u; } cv; cv.h = __float2bfloat16(f); return cv.u;
}

// ---- K1: H = gelu(X @ W1^T + b1) (f32); GHb = bf16(gelu(H)) ----
__global__ __launch_bounds__(512) void k_ff1(const float* __restrict__ X,
    const float* __restrict__ W1, const float* __restrict__ b1,
    float* __restrict__ H, u16* __restrict__ GHb)
{
  extern __shared__ float smem[]; // smem[k*128+c] = W1[c*128+k]
  for (int j = threadIdx.x; j < 128*128; j += 512){
    int k = j >> 7, c = j & 127;
    smem[j] = W1[c*128 + k];
  }
  __syncthreads();
  const int lane = threadIdx.x & 63;
  const int wave = threadIdx.x >> 6;  // 0..7
  const float blo = b1[lane], bhi = b1[lane+64];
  for (int base = (blockIdx.x*8 + wave)*4; base < NN; base += gridDim.x*32){
    const float* x0 = X + (size_t)(base+0)*128;
    const float* x1 = X + (size_t)(base+1)*128;
    const float* x2 = X + (size_t)(base+2)*128;
    const float* x3 = X + (size_t)(base+3)*128;
    float a0x=0,a0y=0,a1x=0,a1y=0,a2x=0,a2y=0,a3x=0,a3y=0;
    for (int k4 = 0; k4 < 128; k4 += 4){
      float4 v0 = *(const float4*)(x0 + k4);
      float4 v1 = *(const float4*)(x1 + k4);
      float4 v2 = *(const float4*)(x2 + k4);
      float4 v3 = *(const float4*)(x3 + k4);
      #define KSTEP(F, KI) { \
        float wa = smem[(k4+KI)*128 + lane]; \
        float wb = smem[(k4+KI)*128 + 64 + lane]; \
        a0x += v0.F*wa; a0y += v0.F*wb; \
        a1x += v1.F*wa; a1y += v1.F*wb; \
        a2x += v2.F*wa; a2y += v2.F*wb; \
        a3x += v3.F*wa; a3y += v3.F*wb; }
      KSTEP(x,0) KSTEP(y,1) KSTEP(z,2) KSTEP(w,3)
      #undef KSTEP
    }
    float h;
    h = geluf(a0x + blo); H[(size_t)(base+0)*128 + lane]    = h; GHb[(size_t)(base+0)*128 + lane]    = f2bfb(geluf(h));
    h = geluf(a0y + bhi); H[(size_t)(base+0)*128 + 64+lane] = h; GHb[(size_t)(base+0)*128 + 64+lane] = f2bfb(geluf(h));
    h = geluf(a1x + blo); H[(size_t)(base+1)*128 + lane]    = h; GHb[(size_t)(base+1)*128 + lane]    = f2bfb(geluf(h));
    h = geluf(a1y + bhi); H[(size_t)(base+1)*128 + 64+lane] = h; GHb[(size_t)(base+1)*128 + 64+lane] = f2bfb(geluf(h));
    h = geluf(a2x + blo); H[(size_t)(base+2)*128 + lane]    = h; GHb[(size_t)(base+2)*128 + lane]    = f2bfb(geluf(h));
    h = geluf(a2y + bhi); H[(size_t)(base+2)*128 + 64+lane] = h; GHb[(size_t)(base+2)*128 + 64+lane] = f2bfb(geluf(h));
    h = geluf(a3x + blo); H[(size_t)(base+3)*128 + lane]    = h; GHb[(size_t)(base+3)*128 + lane]    = f2bfb(geluf(h));
    h = geluf(a3y + bhi); H[(size_t)(base+3)*128 + 64+lane] = h; GHb[(size_t)(base+3)*128 + 64+lane] = f2bfb(geluf(h));
  }
}

// ---------------- sort edges by dst: hist -> scan -> fill(src) ----------------
__global__ void k_hist(const int* __restrict__ dst, int* __restrict__ deg){
  int e = blockIdx.x*256 + threadIdx.x;
  if (e < NE) atomicAdd(&deg[dst[e]], 1);
}

__global__ __launch_bounds__(1024) void k_scan(const int* __restrict__ deg, int* __restrict__ offs){
  __shared__ int wsum[16];
  __shared__ int sbase_s;
  const int tid = threadIdx.x, lane = tid & 63, wave = tid >> 6;
  if (tid == 0) sbase_s = 0;
  __syncthreads();
  for (int base = 0; base < NN; base += 4096){
    int i0 = base + tid*4;
    int v0=0,v1=0,v2=0,v3=0;
    if (i0+3 < NN){ int4 v = *(const int4*)(deg+i0); v0=v.x;v1=v.y;v2=v.z;v3=v.w; }
    else {
      if (i0   < NN) v0 = deg[i0];
      if (i0+1 < NN) v1 = deg[i0+1];
      if (i0+2 < NN) v2 = deg[i0+2];
    }
    int own = v0+v1+v2+v3;
    int inc = own;
    #pragma unroll
    for (int s=1;s<64;s<<=1){ int t = __shfl_up(inc, s, 64); if (lane >= s) inc += t; }
    if (lane == 63) wsum[wave] = inc;
    __syncthreads();
    if (wave == 0 && lane < 16){
      int w = wsum[lane];
      #pragma unroll
      for (int s=1;s<16;s<<=1){ int t = __shfl_up(w, s, 64); if (lane >= s) w += t; }
      wsum[lane] = w;
    }
    __syncthreads();
    int sbase = sbase_s;
    int wbase = sbase + (wave ? wsum[wave-1] : 0);
    int excl = wbase + inc - own;
    if (i0   < NN) offs[i0]   = excl;
    if (i0+1 < NN) offs[i0+1] = excl + v0;
    if (i0+2 < NN) offs[i0+2] = excl + v0+v1;
    if (i0+3 < NN) offs[i0+3] = excl + v0+v1+v2;
    __syncthreads();
    if (tid == 0) sbase_s = sbase + wsum[15];
    __syncthreads();
  }
  if (tid == 0) offs[NN] = sbase_s;
}

__global__ void k_fill(const int* __restrict__ src, const int* __restrict__ dst,
                       const int* __restrict__ offs, int* __restrict__ cur,
                       int* __restrict__ slist){
  int e = blockIdx.x*256 + threadIdx.x;
  if (e < NE){
    int d = dst[e];
    int p = atomicAdd(&cur[d], 1);
    slist[offs[d] + p] = src[e];
  }
}

// ---- K2a: per-NODE T[v] = gelu(H[v] @ WA^T) @ WB^T ----
__global__ __launch_bounds__(512) void k_node(const float* __restrict__ H,
    const float* __restrict__ WA, const float* __restrict__ WB,
    float* __restrict__ T)
{
  extern __shared__ float smem[]; // smem[k*128+h] = WA[h*128+k]
  for (int j = threadIdx.x; j < 128*128; j += 512){
    int k = j >> 7, h = j & 127;
    smem[j] = WA[h*128 + k];
  }
  const int lane = threadIdx.x & 63;
  const int wave = threadIdx.x >> 6;   // 0..7
  float wb0[4], wb1[4];
  #pragma unroll
  for (int m = 0; m < 4; m++){
    wb0[m] = WB[m*128 + lane];
    wb1[m] = WB[m*128 + 64 + lane];
  }
  __syncthreads();
  for (int base = (blockIdx.x*8 + wave)*4; base < NN; base += gridDim.x*32){
    const float* h0 = H + (size_t)(base+0)*128;
    const float* h1 = H + (size_t)(base+1)*128;
    const float* h2 = H + (size_t)(base+2)*128;
    const float* h3 = H + (size_t)(base+3)*128;
    float a0x=0,a0y=0,a1x=0,a1y=0,a2x=0,a2y=0,a3x=0,a3y=0;
    for (int k4 = 0; k4 < 128; k4 += 4){
      float4 v0 = *(const float4*)(h0 + k4);
      float4 v1 = *(const float4*)(h1 + k4);
      float4 v2 = *(const float4*)(h2 + k4);
      float4 v3 = *(const float4*)(h3 + k4);
      #define KSTEP(F, KI) { \
        float wa = smem[(k4+KI)*128 + lane]; \
        float wb = smem[(k4+KI)*128 + 64 + lane]; \
        a0x += v0.F*wa; a0y += v0.F*wb; \
        a1x += v1.F*wa; a1y += v1.F*wb; \
        a2x += v2.F*wa; a2y += v2.F*wb; \
        a3x += v3.F*wa; a3y += v3.F*wb; }
      KSTEP(x,0) KSTEP(y,1) KSTEP(z,2) KSTEP(w,3)
      #undef KSTEP
    }
    float t0x = geluf(a0x), t0y = geluf(a0y);
    float t1x = geluf(a1x), t1y = geluf(a1y);
    float t2x = geluf(a2x), t2y = geluf(a2y);
    float t3x = geluf(a3x), t3y = geluf(a3y);
    float r[16];
    #pragma unroll
    for (int m = 0; m < 4; m++){
      r[0*4+m] = t0x*wb0[m] + t0y*wb1[m];
      r[1*4+m] = t1x*wb0[m] + t1y*wb1[m];
      r[2*4+m] = t2x*wb0[m] + t2y*wb1[m];
      r[3*4+m] = t3x*wb0[m] + t3y*wb1[m];
    }
    #pragma unroll
    for (int s = 1; s < 64; s <<= 1){
      #pragma unroll
      for (int q = 0; q < 16; q++)
        r[q] += __shfl_xor(r[q], s, 64);
    }
    float outv = 0.f;
    #pragma unroll
    for (int q = 0; q < 16; q++)
      if (lane == q) outv = r[q];
    if (lane < 16) T[(size_t)base*4 + lane] = outv;
  }
}

// ------- K2b: per-node aggregation; GAb = bf16(gelu(mean over dst edges)) -------
__global__ __launch_bounds__(256) void k_agg(const float* __restrict__ H,
    const float* __restrict__ T, const int* __restrict__ offs,
    const int* __restrict__ slist, u16* __restrict__ GAb)
{
  const int lane = threadIdx.x & 63;
  const int wave = threadIdx.x >> 6;
  for (int v = blockIdx.x*4 + wave; v < NN; v += gridDim.x*4){
    int e0 = offs[v], e1 = offs[v+1];
    float ax0=0, ax1=0, ax2=0, ax3=0;   // h = 2*lane
    float ay0=0, ay1=0, ay2=0, ay3=0;   // h = 2*lane+1
    float s0=0, s1=0, s2=0, s3=0;
    for (int idx = e0; idx < e1; idx++){
      int sn = slist[idx];
      float2 hv = *(const float2*)(H + (size_t)sn*128 + lane*2);
      float4 wt = *(const float4*)(T + (size_t)sn*4);
      ax0 += hv.x*wt.x; ax1 += hv.x*wt.y; ax2 += hv.x*wt.z; ax3 += hv.x*wt.w;
      ay0 += hv.y*wt.x; ay1 += hv.y*wt.y; ay2 += hv.y*wt.z; ay3 += hv.y*wt.w;
      s0 += wt.x; s1 += wt.y; s2 += wt.z; s3 += wt.w;
    }
    float inv = 1.0f / fmaxf((float)(e1 - e0), 1.0f);
    float ox = geluf(ax0)*s0 + geluf(ax1)*s1 + geluf(ax2)*s2 + geluf(ax3)*s3;
    float oy = geluf(ay0)*s0 + geluf(ay1)*s1 + geluf(ay2)*s2 + geluf(ay3)*s3;
    ushort2 res;
    res.x = f2bfb(geluf(ox * inv));
    res.y = f2bfb(geluf(oy * inv));
    *(ushort2*)(GAb + (size_t)v*128 + lane*2) = res;
  }
}

// ------- K3: out = [GAb, GHb] @ W2^T + b2 via MFMA (bf16 in, f32 out) -------
// A-frag (16x16x32): lane l holds A[row=l&15][k=(l>>4)*8 + j], j=0..7 (16B contiguous)
// B-frag: lane l holds B[k=(l>>4)*8+j][col=l&15] = W2[col][k...] (k-contiguous in W2)
// D: col=lane&15, row=(lane>>4)*4 + reg   [m89-verified]
__global__ __launch_bounds__(512) void k_ff2(const u16* __restrict__ GAb,
    const u16* __restrict__ GHb, const float* __restrict__ W2,
    const float* __restrict__ b2, float* __restrict__ out)
{
  extern __shared__ u16 w2s[];            // [128 o][264 k] bf16, padded rows
  const int LDW = 264;
  for (int idx4 = threadIdx.x*4; idx4 < 128*256; idx4 += 512*4){
    int o = idx4 >> 8, k = idx4 & 255;    // k%4==0
    float4 v = *(const float4*)(W2 + (size_t)o*256 + k);
    ushort2 p0, p1;
    p0.x = f2bfb(v.x); p0.y = f2bfb(v.y);
    p1.x = f2bfb(v.z); p1.y = f2bfb(v.w);
    *(ushort2*)&w2s[o*LDW + k]     = p0;
    *(ushort2*)&w2s[o*LDW + k + 2] = p1;
  }
  __syncthreads();
  const int lane = threadIdx.x & 63;
  const int wave = threadIdx.x >> 6;      // 0..7
  const int lrow = lane & 15;
  const int kgrp = lane >> 4;             // 0..3
  float bias[8];
  #pragma unroll
  for (int nb = 0; nb < 8; nb++) bias[nb] = b2[nb*16 + lrow];
  for (int tile = blockIdx.x*8 + wave; tile < NN/16; tile += gridDim.x*8){
    const int row = tile*16 + lrow;
    const u16* aga = GAb + (size_t)row*128 + kgrp*8;
    const u16* agh = GHb + (size_t)row*128 + kgrp*8;
    f32x4 acc[8];
    #pragma unroll
    for (int nb = 0; nb < 8; nb++) acc[nb] = (f32x4){0.f,0.f,0.f,0.f};
    #pragma unroll
    for (int kk = 0; kk < 8; kk++){
      short8 af = (kk < 4) ? *(const short8*)(aga + kk*32)
                           : *(const short8*)(agh + (kk-4)*32);
      #pragma unroll
      for (int nb = 0; nb < 8; nb++){
        short8 bf = *(const short8*)&w2s[(nb*16 + lrow)*LDW + kk*32 + kgrp*8];
        acc[nb] = __builtin_amdgcn_mfma_f32_16x16x32_bf16(af, bf, acc[nb], 0, 0, 0);
      }
    }
    #pragma unroll
    for (int nb = 0; nb < 8; nb++){
      const int col = nb*16 + lrow;
      #pragma unroll
      for (int r = 0; r < 4; r++){
        int orow = tile*16 + kgrp*4 + r;
        out[(size_t)orow*128 + col] = acc[nb][r] + bias[nb];
      }
    }
  }
}

extern "C" void kernel_launch(void* const* d_in, const int* in_sizes, int n_in,
                              void* d_out, int out_size, void* d_ws, size_t ws_size,
                              hipStream_t stream)
{
  (void)in_sizes; (void)n_in; (void)out_size; (void)ws_size;
  const float* X  = (const float*)d_in[0];
  const int*   ei = (const int*)d_in[1];
  const float* W1 = (const float*)d_in[2];
  const float* b1 = (const float*)d_in[3];
  const float* WA = (const float*)d_in[4];
  const float* WB = (const float*)d_in[5];
  const float* W2 = (const float*)d_in[6];
  const float* b2 = (const float*)d_in[7];
  float* out = (float*)d_out;
  const int* src = ei;
  const int* dst = ei + NE;

  char* p = (char*)d_ws;
  float* H    = (float*)(p);               // 25,600,000 B
  u16*   GHb  = (u16*)(p + 25600000);      // 12,800,000 B
  u16*   GAb  = (u16*)(p + 38400000);      // 12,800,000 B
  float* T    = (float*)(p + 51200000);    //    800,000 B
  int*   deg  = (int*)(p + 52000000);      //    200,192 B
  int*   cur  = (int*)(p + 52200192);      //    200,192 B
  int*   offs = (int*)(p + 52400384);      //    200,448 B
  int*   slist= (int*)(p + 52600832);      //  1,600,000 B  (total ~54.2 MB)

  (void)hipMemsetAsync(deg, 0, 400384, stream);  // zeroes deg + cur (contiguous)

  (void)hipFuncSetAttribute((const void*)k_ff2, hipFuncAttributeMaxDynamicSharedMemorySize, 128*264*2);

  k_ff1 <<<512, 512, 65536, stream>>>(X, W1, b1, H, GHb);
  k_hist<<<(NE+255)/256, 256, 0, stream>>>(dst, deg);
  k_scan<<<1, 1024, 0, stream>>>(deg, offs);
  k_fill<<<(NE+255)/256, 256, 0, stream>>>(src, dst, offs, cur, slist);
  k_node<<<512, 512, 65536, stream>>>(H, WA, WB, T);
  k_agg <<<(NN+3)/4, 256, 0, stream>>>(H, T, offs, slist, GAb);
  k_ff2 <<<392, 512, 128*264*2, stream>>>(GAb, GHb, W2, b2, out);
}

// Round 8
// 200.353 us; speedup vs baseline: 7.5528x; 1.5970x over previous
//
#include <hip/hip_runtime.h>
#include <hip/hip_bf16.h>

#define NN 50000
#define NE 400000
#define NT 3125   // NN/16 row tiles

typedef unsigned short u16;
typedef short short8 __attribute__((ext_vector_type(8)));
typedef float f32x4 __attribute__((ext_vector_type(4)));

__device__ __forceinline__ float geluf(float x){ return 0.5f*x*(1.0f+erff(x*0.70710678118654752440f)); }
__device__ __forceinline__ u16 f2bfb(float f){
  union { __hip_bfloat16 h; u16 u; } cv; cv.h = __float2bfloat16(f); return cv.u;
}
__device__ __forceinline__ float bfb2f(u16 u){ return __uint_as_float(((unsigned)u)<<16); }

// ---- K1 (MFMA): Hb = bf16(gelu(X @ W1^T + b1)); GHb = bf16(gelu(gelu(...)))
// A-frag (16x16x32): lane l holds A[row=l&15][k=(l>>4)*8+j]
// B-frag: lane l holds B[k=(l>>4)*8+j][col=l&15] = W1[col][k..] (k-contig rows)
// D: col=lane&15, row=(lane>>4)*4+reg
__global__ __launch_bounds__(512) void k_ff1(const float* __restrict__ X,
    const float* __restrict__ W1, const float* __restrict__ b1,
    u16* __restrict__ Hb, u16* __restrict__ GHb)
{
  extern __shared__ u16 wls[];            // [128 c][136 k] bf16 padded
  const int LDW = 136;
  for (int idx4 = threadIdx.x*4; idx4 < 128*128; idx4 += 512*4){
    int c = idx4 >> 7, k = idx4 & 127;
    float4 v = *(const float4*)(W1 + (size_t)c*128 + k);
    ushort2 p0, p1;
    p0.x = f2bfb(v.x); p0.y = f2bfb(v.y);
    p1.x = f2bfb(v.z); p1.y = f2bfb(v.w);
    *(ushort2*)&wls[c*LDW + k]     = p0;
    *(ushort2*)&wls[c*LDW + k + 2] = p1;
  }
  __syncthreads();
  const int lane = threadIdx.x & 63;
  const int wave = threadIdx.x >> 6;
  const int lrow = lane & 15;
  const int kgrp = lane >> 4;
  float bias[8];
  #pragma unroll
  for (int nb = 0; nb < 8; nb++) bias[nb] = b1[nb*16 + lrow];
  for (int tile = blockIdx.x*8 + wave; tile < NT; tile += gridDim.x*8){
    const float* xr = X + (size_t)(tile*16 + lrow)*128 + kgrp*8;
    f32x4 acc[8];
    #pragma unroll
    for (int nb = 0; nb < 8; nb++) acc[nb] = (f32x4){0.f,0.f,0.f,0.f};
    #pragma unroll
    for (int kk = 0; kk < 4; kk++){
      float4 xa = *(const float4*)(xr + kk*32);
      float4 xb = *(const float4*)(xr + kk*32 + 4);
      union { short8 v; u16 u[8]; } af;
      af.u[0]=f2bfb(xa.x); af.u[1]=f2bfb(xa.y); af.u[2]=f2bfb(xa.z); af.u[3]=f2bfb(xa.w);
      af.u[4]=f2bfb(xb.x); af.u[5]=f2bfb(xb.y); af.u[6]=f2bfb(xb.z); af.u[7]=f2bfb(xb.w);
      #pragma unroll
      for (int nb = 0; nb < 8; nb++){
        short8 bf = *(const short8*)&wls[(nb*16 + lrow)*LDW + kk*32 + kgrp*8];
        acc[nb] = __builtin_amdgcn_mfma_f32_16x16x32_bf16(af.v, bf, acc[nb], 0, 0, 0);
      }
    }
    #pragma unroll
    for (int nb = 0; nb < 8; nb++){
      const int col = nb*16 + lrow;
      #pragma unroll
      for (int r = 0; r < 4; r++){
        int orow = tile*16 + kgrp*4 + r;
        float h = geluf(acc[nb][r] + bias[nb]);
        Hb [(size_t)orow*128 + col] = f2bfb(h);
        GHb[(size_t)orow*128 + col] = f2bfb(geluf(h));
      }
    }
  }
}

// ---------------- sort edges by dst: hist -> scan -> fill(src) ----------------
__global__ void k_hist(const int* __restrict__ dst, int* __restrict__ deg){
  int e = blockIdx.x*256 + threadIdx.x;
  if (e < NE) atomicAdd(&deg[dst[e]], 1);
}

__global__ __launch_bounds__(1024) void k_scan(const int* __restrict__ deg, int* __restrict__ offs){
  __shared__ int wsum[16];
  __shared__ int sbase_s;
  const int tid = threadIdx.x, lane = tid & 63, wave = tid >> 6;
  if (tid == 0) sbase_s = 0;
  __syncthreads();
  for (int base = 0; base < NN; base += 4096){
    int i0 = base + tid*4;
    int v0=0,v1=0,v2=0,v3=0;
    if (i0+3 < NN){ int4 v = *(const int4*)(deg+i0); v0=v.x;v1=v.y;v2=v.z;v3=v.w; }
    else {
      if (i0   < NN) v0 = deg[i0];
      if (i0+1 < NN) v1 = deg[i0+1];
      if (i0+2 < NN) v2 = deg[i0+2];
    }
    int own = v0+v1+v2+v3;
    int inc = own;
    #pragma unroll
    for (int s=1;s<64;s<<=1){ int t = __shfl_up(inc, s, 64); if (lane >= s) inc += t; }
    if (lane == 63) wsum[wave] = inc;
    __syncthreads();
    if (wave == 0 && lane < 16){
      int w = wsum[lane];
      #pragma unroll
      for (int s=1;s<16;s<<=1){ int t = __shfl_up(w, s, 64); if (lane >= s) w += t; }
      wsum[lane] = w;
    }
    __syncthreads();
    int sbase = sbase_s;
    int wbase = sbase + (wave ? wsum[wave-1] : 0);
    int excl = wbase + inc - own;
    if (i0   < NN) offs[i0]   = excl;
    if (i0+1 < NN) offs[i0+1] = excl + v0;
    if (i0+2 < NN) offs[i0+2] = excl + v0+v1;
    if (i0+3 < NN) offs[i0+3] = excl + v0+v1+v2;
    __syncthreads();
    if (tid == 0) sbase_s = sbase + wsum[15];
    __syncthreads();
  }
  if (tid == 0) offs[NN] = sbase_s;
}

__global__ void k_fill(const int* __restrict__ src, const int* __restrict__ dst,
                       const int* __restrict__ offs, int* __restrict__ cur,
                       int* __restrict__ slist){
  int e = blockIdx.x*256 + threadIdx.x;
  if (e < NE){
    int d = dst[e];
    int p = atomicAdd(&cur[d], 1);
    slist[offs[d] + p] = src[e];
  }
}

// ---- K2a (MFMA): T[v][m] = gelu(Hb[v] @ WA^T) @ WB^T ----
__global__ __launch_bounds__(512) void k_node(const u16* __restrict__ Hb,
    const float* __restrict__ WA, const float* __restrict__ WB,
    float* __restrict__ T)
{
  extern __shared__ u16 was[];            // [128 h][136 k] bf16 padded
  const int LDW = 136;
  for (int idx4 = threadIdx.x*4; idx4 < 128*128; idx4 += 512*4){
    int h = idx4 >> 7, k = idx4 & 127;
    float4 v = *(const float4*)(WA + (size_t)h*128 + k);
    ushort2 p0, p1;
    p0.x = f2bfb(v.x); p0.y = f2bfb(v.y);
    p1.x = f2bfb(v.z); p1.y = f2bfb(v.w);
    *(ushort2*)&was[h*LDW + k]     = p0;
    *(ushort2*)&was[h*LDW + k + 2] = p1;
  }
  const int lane = threadIdx.x & 63;
  const int wave = threadIdx.x >> 6;
  const int lrow = lane & 15;
  const int kgrp = lane >> 4;
  float wbv[4][8];
  #pragma unroll
  for (int m = 0; m < 4; m++)
    #pragma unroll
    for (int nb = 0; nb < 8; nb++)
      wbv[m][nb] = WB[m*128 + nb*16 + lrow];
  __syncthreads();
  for (int tile = blockIdx.x*8 + wave; tile < NT; tile += gridDim.x*8){
    const u16* hr = Hb + (size_t)(tile*16 + lrow)*128 + kgrp*8;
    f32x4 acc[8];
    #pragma unroll
    for (int nb = 0; nb < 8; nb++) acc[nb] = (f32x4){0.f,0.f,0.f,0.f};
    #pragma unroll
    for (int kk = 0; kk < 4; kk++){
      short8 af = *(const short8*)(hr + kk*32);
      #pragma unroll
      for (int nb = 0; nb < 8; nb++){
        short8 bf = *(const short8*)&was[(nb*16 + lrow)*LDW + kk*32 + kgrp*8];
        acc[nb] = __builtin_amdgcn_mfma_f32_16x16x32_bf16(af, bf, acc[nb], 0, 0, 0);
      }
    }
    float part[4][4];   // [reg r][m]
    #pragma unroll
    for (int r = 0; r < 4; r++)
      #pragma unroll
      for (int m = 0; m < 4; m++) part[r][m] = 0.f;
    #pragma unroll
    for (int nb = 0; nb < 8; nb++){
      float g0 = geluf(acc[nb][0]), g1 = geluf(acc[nb][1]);
      float g2 = geluf(acc[nb][2]), g3 = geluf(acc[nb][3]);
      #pragma unroll
      for (int m = 0; m < 4; m++){
        float w = wbv[m][nb];
        part[0][m] += g0*w; part[1][m] += g1*w;
        part[2][m] += g2*w; part[3][m] += g3*w;
      }
    }
    #pragma unroll
    for (int s = 1; s < 16; s <<= 1)
      #pragma unroll
      for (int r = 0; r < 4; r++)
        #pragma unroll
        for (int m = 0; m < 4; m++)
          part[r][m] += __shfl_xor(part[r][m], s, 64);
    if (lrow == 0){
      #pragma unroll
      for (int r = 0; r < 4; r++){
        f32x4 tv = { part[r][0], part[r][1], part[r][2], part[r][3] };
        *(f32x4*)&T[(size_t)(tile*16 + kgrp*4 + r)*4] = tv;
      }
    }
  }
}

// ------- K2b: per-node aggregation (bf16 H gather); GAb = bf16(gelu(mean)) -------
__global__ __launch_bounds__(256) void k_agg(const u16* __restrict__ Hb,
    const float* __restrict__ T, const int* __restrict__ offs,
    const int* __restrict__ slist, u16* __restrict__ GAb)
{
  const int lane = threadIdx.x & 63;
  const int wave = threadIdx.x >> 6;
  for (int v = blockIdx.x*4 + wave; v < NN; v += gridDim.x*4){
    int e0 = offs[v], e1 = offs[v+1];
    float ax0=0, ax1=0, ax2=0, ax3=0;   // h = 2*lane
    float ay0=0, ay1=0, ay2=0, ay3=0;   // h = 2*lane+1
    float s0=0, s1=0, s2=0, s3=0;
    for (int idx = e0; idx < e1; idx++){
      int sn = slist[idx];
      unsigned pk = *(const unsigned*)(Hb + (size_t)sn*128 + lane*2);
      float hx = bfb2f((u16)(pk & 0xffffu));
      float hy = bfb2f((u16)(pk >> 16));
      float4 wt = *(const float4*)(T + (size_t)sn*4);
      ax0 += hx*wt.x; ax1 += hx*wt.y; ax2 += hx*wt.z; ax3 += hx*wt.w;
      ay0 += hy*wt.x; ay1 += hy*wt.y; ay2 += hy*wt.z; ay3 += hy*wt.w;
      s0 += wt.x; s1 += wt.y; s2 += wt.z; s3 += wt.w;
    }
    float inv = 1.0f / fmaxf((float)(e1 - e0), 1.0f);
    float ox = geluf(ax0)*s0 + geluf(ax1)*s1 + geluf(ax2)*s2 + geluf(ax3)*s3;
    float oy = geluf(ay0)*s0 + geluf(ay1)*s1 + geluf(ay2)*s2 + geluf(ay3)*s3;
    ushort2 res;
    res.x = f2bfb(geluf(ox * inv));
    res.y = f2bfb(geluf(oy * inv));
    *(ushort2*)(GAb + (size_t)v*128 + lane*2) = res;
  }
}

// ------- K3 (MFMA): out = [GAb, GHb] @ W2^T + b2 -------
__global__ __launch_bounds__(512) void k_ff2(const u16* __restrict__ GAb,
    const u16* __restrict__ GHb, const float* __restrict__ W2,
    const float* __restrict__ b2, float* __restrict__ out)
{
  extern __shared__ u16 w2s[];            // [128 o][264 k] bf16 padded
  const int LDW = 264;
  for (int idx4 = threadIdx.x*4; idx4 < 128*256; idx4 += 512*4){
    int o = idx4 >> 8, k = idx4 & 255;
    float4 v = *(const float4*)(W2 + (size_t)o*256 + k);
    ushort2 p0, p1;
    p0.x = f2bfb(v.x); p0.y = f2bfb(v.y);
    p1.x = f2bfb(v.z); p1.y = f2bfb(v.w);
    *(ushort2*)&w2s[o*LDW + k]     = p0;
    *(ushort2*)&w2s[o*LDW + k + 2] = p1;
  }
  __syncthreads();
  const int lane = threadIdx.x & 63;
  const int wave = threadIdx.x >> 6;
  const int lrow = lane & 15;
  const int kgrp = lane >> 4;
  float bias[8];
  #pragma unroll
  for (int nb = 0; nb < 8; nb++) bias[nb] = b2[nb*16 + lrow];
  for (int tile = blockIdx.x*8 + wave; tile < NT; tile += gridDim.x*8){
    const int row = tile*16 + lrow;
    const u16* aga = GAb + (size_t)row*128 + kgrp*8;
    const u16* agh = GHb + (size_t)row*128 + kgrp*8;
    f32x4 acc[8];
    #pragma unroll
    for (int nb = 0; nb < 8; nb++) acc[nb] = (f32x4){0.f,0.f,0.f,0.f};
    #pragma unroll
    for (int kk = 0; kk < 8; kk++){
      short8 af = (kk < 4) ? *(const short8*)(aga + kk*32)
                           : *(const short8*)(agh + (kk-4)*32);
      #pragma unroll
      for (int nb = 0; nb < 8; nb++){
        short8 bf = *(const short8*)&w2s[(nb*16 + lrow)*LDW + kk*32 + kgrp*8];
        acc[nb] = __builtin_amdgcn_mfma_f32_16x16x32_bf16(af, bf, acc[nb], 0, 0, 0);
      }
    }
    #pragma unroll
    for (int nb = 0; nb < 8; nb++){
      const int col = nb*16 + lrow;
      #pragma unroll
      for (int r = 0; r < 4; r++){
        int orow = tile*16 + kgrp*4 + r;
        out[(size_t)orow*128 + col] = acc[nb][r] + bias[nb];
      }
    }
  }
}

extern "C" void kernel_launch(void* const* d_in, const int* in_sizes, int n_in,
                              void* d_out, int out_size, void* d_ws, size_t ws_size,
                              hipStream_t stream)
{
  (void)in_sizes; (void)n_in; (void)out_size; (void)ws_size;
  const float* X  = (const float*)d_in[0];
  const int*   ei = (const int*)d_in[1];
  const float* W1 = (const float*)d_in[2];
  const float* b1 = (const float*)d_in[3];
  const float* WA = (const float*)d_in[4];
  const float* WB = (const float*)d_in[5];
  const float* W2 = (const float*)d_in[6];
  const float* b2 = (const float*)d_in[7];
  float* out = (float*)d_out;
  const int* src = ei;
  const int* dst = ei + NE;

  char* p = (char*)d_ws;
  u16*   Hb   = (u16*)(p);                 // 12,800,000 B
  u16*   GHb  = (u16*)(p + 12800000);      // 12,800,000 B
  u16*   GAb  = (u16*)(p + 25600000);      // 12,800,000 B
  float* T    = (float*)(p + 38400000);    //    800,000 B
  int*   deg  = (int*)(p + 39200000);      //    200,192 B
  int*   cur  = (int*)(p + 39400192);      //    200,192 B
  int*   offs = (int*)(p + 39600384);      //    200,448 B
  int*   slist= (int*)(p + 39800832);      //  1,600,000 B  (total ~41.4 MB)

  (void)hipMemsetAsync(deg, 0, 400384, stream);  // zeroes deg + cur (contiguous)

  (void)hipFuncSetAttribute((const void*)k_ff2, hipFuncAttributeMaxDynamicSharedMemorySize, 128*264*2);

  k_ff1 <<<391, 512, 128*136*2, stream>>>(X, W1, b1, Hb, GHb);
  k_hist<<<(NE+255)/256, 256, 0, stream>>>(dst, deg);
  k_scan<<<1, 1024, 0, stream>>>(deg, offs);
  k_fill<<<(NE+255)/256, 256, 0, stream>>>(src, dst, offs, cur, slist);
  k_node<<<391, 512, 128*136*2, stream>>>(Hb, WA, WB, T);
  k_agg <<<(NN+3)/4, 256, 0, stream>>>(Hb, T, offs, slist, GAb);
  k_ff2 <<<391, 512, 128*264*2, stream>>>(GAb, GHb, W2, b2, out);
}

// Round 9
// 181.729 us; speedup vs baseline: 8.3268x; 1.1025x over previous
//
#include <hip/hip_runtime.h>
#include <hip/hip_bf16.h>

#define NN 50000
#define NE 400000
#define NT 3125   // NN/16 row tiles

typedef unsigned short u16;
typedef short short8 __attribute__((ext_vector_type(8)));
typedef float f32x4 __attribute__((ext_vector_type(4)));

__device__ __forceinline__ float geluf(float x){ return 0.5f*x*(1.0f+erff(x*0.70710678118654752440f)); }
__device__ __forceinline__ u16 f2bfb(float f){
  union { __hip_bfloat16 h; u16 u; } cv; cv.h = __float2bfloat16(f); return cv.u;
}
__device__ __forceinline__ float bfb2f(u16 u){ return __uint_as_float(((unsigned)u)<<16); }

// ---- K1 (MFMA): Hb = bf16(gelu(X @ W1^T + b1)); GHb = bf16(gelu(gelu(...)))
__global__ __launch_bounds__(512) void k_ff1(const float* __restrict__ X,
    const float* __restrict__ W1, const float* __restrict__ b1,
    u16* __restrict__ Hb, u16* __restrict__ GHb)
{
  extern __shared__ u16 wls[];            // [128 c][136 k] bf16 padded
  const int LDW = 136;
  for (int idx4 = threadIdx.x*4; idx4 < 128*128; idx4 += 512*4){
    int c = idx4 >> 7, k = idx4 & 127;
    float4 v = *(const float4*)(W1 + (size_t)c*128 + k);
    ushort2 p0, p1;
    p0.x = f2bfb(v.x); p0.y = f2bfb(v.y);
    p1.x = f2bfb(v.z); p1.y = f2bfb(v.w);
    *(ushort2*)&wls[c*LDW + k]     = p0;
    *(ushort2*)&wls[c*LDW + k + 2] = p1;
  }
  __syncthreads();
  const int lane = threadIdx.x & 63;
  const int wave = threadIdx.x >> 6;
  const int lrow = lane & 15;
  const int kgrp = lane >> 4;
  float bias[8];
  #pragma unroll
  for (int nb = 0; nb < 8; nb++) bias[nb] = b1[nb*16 + lrow];
  for (int tile = blockIdx.x*8 + wave; tile < NT; tile += gridDim.x*8){
    const float* xr = X + (size_t)(tile*16 + lrow)*128 + kgrp*8;
    f32x4 acc[8];
    #pragma unroll
    for (int nb = 0; nb < 8; nb++) acc[nb] = (f32x4){0.f,0.f,0.f,0.f};
    #pragma unroll
    for (int kk = 0; kk < 4; kk++){
      float4 xa = *(const float4*)(xr + kk*32);
      float4 xb = *(const float4*)(xr + kk*32 + 4);
      union { short8 v; u16 u[8]; } af;
      af.u[0]=f2bfb(xa.x); af.u[1]=f2bfb(xa.y); af.u[2]=f2bfb(xa.z); af.u[3]=f2bfb(xa.w);
      af.u[4]=f2bfb(xb.x); af.u[5]=f2bfb(xb.y); af.u[6]=f2bfb(xb.z); af.u[7]=f2bfb(xb.w);
      #pragma unroll
      for (int nb = 0; nb < 8; nb++){
        short8 bf = *(const short8*)&wls[(nb*16 + lrow)*LDW + kk*32 + kgrp*8];
        acc[nb] = __builtin_amdgcn_mfma_f32_16x16x32_bf16(af.v, bf, acc[nb], 0, 0, 0);
      }
    }
    #pragma unroll
    for (int nb = 0; nb < 8; nb++){
      const int col = nb*16 + lrow;
      #pragma unroll
      for (int r = 0; r < 4; r++){
        int orow = tile*16 + kgrp*4 + r;
        float h = geluf(acc[nb][r] + bias[nb]);
        Hb [(size_t)orow*128 + col] = f2bfb(h);
        GHb[(size_t)orow*128 + col] = f2bfb(geluf(h));
      }
    }
  }
}

// ---------------- sort edges by dst: hist -> scan -> fill(src) ----------------
__global__ void k_hist(const int* __restrict__ dst, int* __restrict__ deg){
  int e = blockIdx.x*256 + threadIdx.x;
  if (e < NE) atomicAdd(&deg[dst[e]], 1);
}

__global__ __launch_bounds__(1024) void k_scan(const int* __restrict__ deg, int* __restrict__ offs){
  __shared__ int wsum[16];
  __shared__ int sbase_s;
  const int tid = threadIdx.x, lane = tid & 63, wave = tid >> 6;
  if (tid == 0) sbase_s = 0;
  __syncthreads();
  for (int base = 0; base < NN; base += 4096){
    int i0 = base + tid*4;
    int v0=0,v1=0,v2=0,v3=0;
    if (i0+3 < NN){ int4 v = *(const int4*)(deg+i0); v0=v.x;v1=v.y;v2=v.z;v3=v.w; }
    else {
      if (i0   < NN) v0 = deg[i0];
      if (i0+1 < NN) v1 = deg[i0+1];
      if (i0+2 < NN) v2 = deg[i0+2];
    }
    int own = v0+v1+v2+v3;
    int inc = own;
    #pragma unroll
    for (int s=1;s<64;s<<=1){ int t = __shfl_up(inc, s, 64); if (lane >= s) inc += t; }
    if (lane == 63) wsum[wave] = inc;
    __syncthreads();
    if (wave == 0 && lane < 16){
      int w = wsum[lane];
      #pragma unroll
      for (int s=1;s<16;s<<=1){ int t = __shfl_up(w, s, 64); if (lane >= s) w += t; }
      wsum[lane] = w;
    }
    __syncthreads();
    int sbase = sbase_s;
    int wbase = sbase + (wave ? wsum[wave-1] : 0);
    int excl = wbase + inc - own;
    if (i0   < NN) offs[i0]   = excl;
    if (i0+1 < NN) offs[i0+1] = excl + v0;
    if (i0+2 < NN) offs[i0+2] = excl + v0+v1;
    if (i0+3 < NN) offs[i0+3] = excl + v0+v1+v2;
    __syncthreads();
    if (tid == 0) sbase_s = sbase + wsum[15];
    __syncthreads();
  }
  if (tid == 0) offs[NN] = sbase_s;
}

__global__ void k_fill(const int* __restrict__ src, const int* __restrict__ dst,
                       const int* __restrict__ offs, int* __restrict__ cur,
                       int* __restrict__ slist){
  int e = blockIdx.x*256 + threadIdx.x;
  if (e < NE){
    int d = dst[e];
    int p = atomicAdd(&cur[d], 1);
    slist[offs[d] + p] = src[e];
  }
}

// ---- K2a (MFMA): T[v][m] = gelu(Hb[v] @ WA^T) @ WB^T ----
__global__ __launch_bounds__(512) void k_node(const u16* __restrict__ Hb,
    const float* __restrict__ WA, const float* __restrict__ WB,
    float* __restrict__ T)
{
  extern __shared__ u16 was[];            // [128 h][136 k] bf16 padded
  const int LDW = 136;
  for (int idx4 = threadIdx.x*4; idx4 < 128*128; idx4 += 512*4){
    int h = idx4 >> 7, k = idx4 & 127;
    float4 v = *(const float4*)(WA + (size_t)h*128 + k);
    ushort2 p0, p1;
    p0.x = f2bfb(v.x); p0.y = f2bfb(v.y);
    p1.x = f2bfb(v.z); p1.y = f2bfb(v.w);
    *(ushort2*)&was[h*LDW + k]     = p0;
    *(ushort2*)&was[h*LDW + k + 2] = p1;
  }
  const int lane = threadIdx.x & 63;
  const int wave = threadIdx.x >> 6;
  const int lrow = lane & 15;
  const int kgrp = lane >> 4;
  float wbv[4][8];
  #pragma unroll
  for (int m = 0; m < 4; m++)
    #pragma unroll
    for (int nb = 0; nb < 8; nb++)
      wbv[m][nb] = WB[m*128 + nb*16 + lrow];
  __syncthreads();
  for (int tile = blockIdx.x*8 + wave; tile < NT; tile += gridDim.x*8){
    const u16* hr = Hb + (size_t)(tile*16 + lrow)*128 + kgrp*8;
    f32x4 acc[8];
    #pragma unroll
    for (int nb = 0; nb < 8; nb++) acc[nb] = (f32x4){0.f,0.f,0.f,0.f};
    #pragma unroll
    for (int kk = 0; kk < 4; kk++){
      short8 af = *(const short8*)(hr + kk*32);
      #pragma unroll
      for (int nb = 0; nb < 8; nb++){
        short8 bf = *(const short8*)&was[(nb*16 + lrow)*LDW + kk*32 + kgrp*8];
        acc[nb] = __builtin_amdgcn_mfma_f32_16x16x32_bf16(af, bf, acc[nb], 0, 0, 0);
      }
    }
    float part[4][4];   // [reg r][m]
    #pragma unroll
    for (int r = 0; r < 4; r++)
      #pragma unroll
      for (int m = 0; m < 4; m++) part[r][m] = 0.f;
    #pragma unroll
    for (int nb = 0; nb < 8; nb++){
      float g0 = geluf(acc[nb][0]), g1 = geluf(acc[nb][1]);
      float g2 = geluf(acc[nb][2]), g3 = geluf(acc[nb][3]);
      #pragma unroll
      for (int m = 0; m < 4; m++){
        float w = wbv[m][nb];
        part[0][m] += g0*w; part[1][m] += g1*w;
        part[2][m] += g2*w; part[3][m] += g3*w;
      }
    }
    #pragma unroll
    for (int s = 1; s < 16; s <<= 1)
      #pragma unroll
      for (int r = 0; r < 4; r++)
        #pragma unroll
        for (int m = 0; m < 4; m++)
          part[r][m] += __shfl_xor(part[r][m], s, 64);
    if (lrow == 0){
      #pragma unroll
      for (int r = 0; r < 4; r++){
        f32x4 tv = { part[r][0], part[r][1], part[r][2], part[r][3] };
        *(f32x4*)&T[(size_t)(tile*16 + kgrp*4 + r)*4] = tv;
      }
    }
  }
}

// ------- K2b: per-node aggregation, 4-edge unrolled gather (MLP) -------
__global__ __launch_bounds__(256) void k_agg(const u16* __restrict__ Hb,
    const float* __restrict__ T, const int* __restrict__ offs,
    const int* __restrict__ slist, u16* __restrict__ GAb)
{
  const int lane = threadIdx.x & 63;
  const int wave = threadIdx.x >> 6;
  int v = blockIdx.x*4 + wave;
  if (v >= NN) return;
  int e0 = offs[v], e1 = offs[v+1];
  float ax0=0, ax1=0, ax2=0, ax3=0;   // h = 2*lane
  float ay0=0, ay1=0, ay2=0, ay3=0;   // h = 2*lane+1
  float s0=0, s1=0, s2=0, s3=0;
  int idx = e0;
  for (; idx + 4 <= e1; idx += 4){
    int sa = slist[idx+0], sb = slist[idx+1], sc = slist[idx+2], sd = slist[idx+3];
    unsigned pa = *(const unsigned*)(Hb + (size_t)sa*128 + lane*2);
    unsigned pb = *(const unsigned*)(Hb + (size_t)sb*128 + lane*2);
    unsigned pc = *(const unsigned*)(Hb + (size_t)sc*128 + lane*2);
    unsigned pd = *(const unsigned*)(Hb + (size_t)sd*128 + lane*2);
    float4 ta = *(const float4*)(T + (size_t)sa*4);
    float4 tb = *(const float4*)(T + (size_t)sb*4);
    float4 tc = *(const float4*)(T + (size_t)sc*4);
    float4 td = *(const float4*)(T + (size_t)sd*4);
    float hx, hy;
    hx = bfb2f((u16)(pa & 0xffffu)); hy = bfb2f((u16)(pa >> 16));
    ax0 += hx*ta.x; ax1 += hx*ta.y; ax2 += hx*ta.z; ax3 += hx*ta.w;
    ay0 += hy*ta.x; ay1 += hy*ta.y; ay2 += hy*ta.z; ay3 += hy*ta.w;
    s0 += ta.x; s1 += ta.y; s2 += ta.z; s3 += ta.w;
    hx = bfb2f((u16)(pb & 0xffffu)); hy = bfb2f((u16)(pb >> 16));
    ax0 += hx*tb.x; ax1 += hx*tb.y; ax2 += hx*tb.z; ax3 += hx*tb.w;
    ay0 += hy*tb.x; ay1 += hy*tb.y; ay2 += hy*tb.z; ay3 += hy*tb.w;
    s0 += tb.x; s1 += tb.y; s2 += tb.z; s3 += tb.w;
    hx = bfb2f((u16)(pc & 0xffffu)); hy = bfb2f((u16)(pc >> 16));
    ax0 += hx*tc.x; ax1 += hx*tc.y; ax2 += hx*tc.z; ax3 += hx*tc.w;
    ay0 += hy*tc.x; ay1 += hy*tc.y; ay2 += hy*tc.z; ay3 += hy*tc.w;
    s0 += tc.x; s1 += tc.y; s2 += tc.z; s3 += tc.w;
    hx = bfb2f((u16)(pd & 0xffffu)); hy = bfb2f((u16)(pd >> 16));
    ax0 += hx*td.x; ax1 += hx*td.y; ax2 += hx*td.z; ax3 += hx*td.w;
    ay0 += hy*td.x; ay1 += hy*td.y; ay2 += hy*td.z; ay3 += hy*td.w;
    s0 += td.x; s1 += td.y; s2 += td.z; s3 += td.w;
  }
  for (; idx < e1; idx++){
    int sn = slist[idx];
    unsigned pk = *(const unsigned*)(Hb + (size_t)sn*128 + lane*2);
    float hx = bfb2f((u16)(pk & 0xffffu));
    float hy = bfb2f((u16)(pk >> 16));
    float4 wt = *(const float4*)(T + (size_t)sn*4);
    ax0 += hx*wt.x; ax1 += hx*wt.y; ax2 += hx*wt.z; ax3 += hx*wt.w;
    ay0 += hy*wt.x; ay1 += hy*wt.y; ay2 += hy*wt.z; ay3 += hy*wt.w;
    s0 += wt.x; s1 += wt.y; s2 += wt.z; s3 += wt.w;
  }
  float inv = 1.0f / fmaxf((float)(e1 - e0), 1.0f);
  float ox = geluf(ax0)*s0 + geluf(ax1)*s1 + geluf(ax2)*s2 + geluf(ax3)*s3;
  float oy = geluf(ay0)*s0 + geluf(ay1)*s1 + geluf(ay2)*s2 + geluf(ay3)*s3;
  ushort2 res;
  res.x = f2bfb(geluf(ox * inv));
  res.y = f2bfb(geluf(oy * inv));
  *(ushort2*)(GAb + (size_t)v*128 + lane*2) = res;
}

// ------- K3 (MFMA): out = [GAb, GHb] @ W2^T + b2 -------
__global__ __launch_bounds__(512) void k_ff2(const u16* __restrict__ GAb,
    const u16* __restrict__ GHb, const float* __restrict__ W2,
    const float* __restrict__ b2, float* __restrict__ out)
{
  extern __shared__ u16 w2s[];            // [128 o][264 k] bf16 padded
  const int LDW = 264;
  for (int idx4 = threadIdx.x*4; idx4 < 128*256; idx4 += 512*4){
    int o = idx4 >> 8, k = idx4 & 255;
    float4 v = *(const float4*)(W2 + (size_t)o*256 + k);
    ushort2 p0, p1;
    p0.x = f2bfb(v.x); p0.y = f2bfb(v.y);
    p1.x = f2bfb(v.z); p1.y = f2bfb(v.w);
    *(ushort2*)&w2s[o*LDW + k]     = p0;
    *(ushort2*)&w2s[o*LDW + k + 2] = p1;
  }
  __syncthreads();
  const int lane = threadIdx.x & 63;
  const int wave = threadIdx.x >> 6;
  const int lrow = lane & 15;
  const int kgrp = lane >> 4;
  float bias[8];
  #pragma unroll
  for (int nb = 0; nb < 8; nb++) bias[nb] = b2[nb*16 + lrow];
  for (int tile = blockIdx.x*8 + wave; tile < NT; tile += gridDim.x*8){
    const int row = tile*16 + lrow;
    const u16* aga = GAb + (size_t)row*128 + kgrp*8;
    const u16* agh = GHb + (size_t)row*128 + kgrp*8;
    f32x4 acc[8];
    #pragma unroll
    for (int nb = 0; nb < 8; nb++) acc[nb] = (f32x4){0.f,0.f,0.f,0.f};
    #pragma unroll
    for (int kk = 0; kk < 8; kk++){
      short8 af = (kk < 4) ? *(const short8*)(aga + kk*32)
                           : *(const short8*)(agh + (kk-4)*32);
      #pragma unroll
      for (int nb = 0; nb < 8; nb++){
        short8 bf = *(const short8*)&w2s[(nb*16 + lrow)*LDW + kk*32 + kgrp*8];
        acc[nb] = __builtin_amdgcn_mfma_f32_16x16x32_bf16(af, bf, acc[nb], 0, 0, 0);
      }
    }
    #pragma unroll
    for (int nb = 0; nb < 8; nb++){
      const int col = nb*16 + lrow;
      #pragma unroll
      for (int r = 0; r < 4; r++){
        int orow = tile*16 + kgrp*4 + r;
        out[(size_t)orow*128 + col] = acc[nb][r] + bias[nb];
      }
    }
  }
}

extern "C" void kernel_launch(void* const* d_in, const int* in_sizes, int n_in,
                              void* d_out, int out_size, void* d_ws, size_t ws_size,
                              hipStream_t stream)
{
  (void)in_sizes; (void)n_in; (void)out_size; (void)ws_size;
  const float* X  = (const float*)d_in[0];
  const int*   ei = (const int*)d_in[1];
  const float* W1 = (const float*)d_in[2];
  const float* b1 = (const float*)d_in[3];
  const float* WA = (const float*)d_in[4];
  const float* WB = (const float*)d_in[5];
  const float* W2 = (const float*)d_in[6];
  const float* b2 = (const float*)d_in[7];
  float* out = (float*)d_out;
  const int* src = ei;
  const int* dst = ei + NE;

  char* p = (char*)d_ws;
  u16*   Hb   = (u16*)(p);                 // 12,800,000 B
  u16*   GHb  = (u16*)(p + 12800000);      // 12,800,000 B
  u16*   GAb  = (u16*)(p + 25600000);      // 12,800,000 B
  float* T    = (float*)(p + 38400000);    //    800,000 B
  int*   deg  = (int*)(p + 39200000);      //    200,192 B
  int*   cur  = (int*)(p + 39400192);      //    200,192 B
  int*   offs = (int*)(p + 39600384);      //    200,448 B
  int*   slist= (int*)(p + 39800832);      //  1,600,000 B  (total ~41.4 MB)

  (void)hipMemsetAsync(deg, 0, 400384, stream);  // zeroes deg + cur (contiguous)

  (void)hipFuncSetAttribute((const void*)k_ff2, hipFuncAttributeMaxDynamicSharedMemorySize, 128*264*2);

  k_ff1 <<<391, 512, 128*136*2, stream>>>(X, W1, b1, Hb, GHb);
  k_hist<<<(NE+255)/256, 256, 0, stream>>>(dst, deg);
  k_scan<<<1, 1024, 0, stream>>>(deg, offs);
  k_fill<<<(NE+255)/256, 256, 0, stream>>>(src, dst, offs, cur, slist);
  k_node<<<391, 512, 128*136*2, stream>>>(Hb, WA, WB, T);
  k_agg <<<(NN+3)/4, 256, 0, stream>>>(Hb, T, offs, slist, GAb);
  k_ff2 <<<391, 512, 128*264*2, stream>>>(GAb, GHb, W2, b2, out);
}